// Round 6
// baseline (348.994 us; speedup 1.0000x reference)
//
#include <hip/hip_runtime.h>
#include <hip/hip_bf16.h>

#define NANCH 202500
#define PRE_NMS 6000
#define POST_NMS 300
#define KW 94            // ceil(6016/64) words per supp row
#define CAP 8192
#define NBUCK 8192
#define BSHIFT 19
#define IOU_TH 0.7f
#define MIN_SIZE 0.016f
#define TB_PAD 6016
#define RITEMS 8
#define RTILE 256
#define NBLK 128         // fused grid (co-resident: 52KB LDS -> 3 blocks/CU cap = 768)
#define NTHR 256
#define SBLK 256         // fallback k_score grid

typedef unsigned long long ull;

// ---------------- shared decode / key helpers ---------------------------
__device__ inline float4 decode_box(const float* __restrict__ loc,
                                    const float* __restrict__ anc, int i) {
    float4 a = ((const float4*)anc)[i];
    float4 t = ((const float4*)loc)[i];
    float pw = a.z - a.x, ph = a.w - a.y;
    float pcx = (a.x + a.z) * 0.5f, pcy = (a.y + a.w) * 0.5f;
    float cx = t.x * pw + pcx, cy = t.y * ph + pcy;
    float w = expf(t.z) * pw, h = expf(t.w) * ph;
    float x1 = fminf(fmaxf(cx - 0.5f * w, 0.f), 1.f);
    float y1 = fminf(fmaxf(cy - 0.5f * h, 0.f), 1.f);
    float x2 = fminf(fmaxf(cx + 0.5f * w, 0.f), 1.f);
    float y2 = fminf(fmaxf(cy + 0.5f * h, 0.f), 1.f);
    return make_float4(x1, y1, x2, y2);
}

__device__ inline unsigned make_key(const float* __restrict__ cls,
                                    const float* __restrict__ loc,
                                    const float* __restrict__ anc, int i) {
    float2 c = ((const float2*)cls)[i];
    float d = c.y - c.x;                       // monotone proxy for softmax[:,1]
    float4 b = decode_box(loc, anc, i);
    bool valid = ((b.z - b.x) >= MIN_SIZE) && ((b.w - b.y) >= MIN_SIZE);
    unsigned ib = __float_as_uint(d);
    unsigned u = (ib & 0x80000000u) ? ~ib : (ib | 0x80000000u);  // monotonic key
    return valid ? u : 0u;
}

__device__ inline ull bcast64(ull v, int lane) {
    unsigned lo = (unsigned)v, hi = (unsigned)(v >> 32);
    lo = (unsigned)__shfl((int)lo, lane, 64);
    hi = (unsigned)__shfl((int)hi, lane, 64);
    return ((ull)hi << 32) | lo;
}

// grid barrier: counter arrive + spin. __threadfence() = agent-scope fence
// (L2 writeback on release side, L1/L2 invalidate on acquire side) -> handles
// cross-XCD visibility (G16). __syncthreads before arrive drains each wave's
// stores (compiler emits vmcnt(0) before s_barrier).
__device__ inline void gsync(unsigned* bar, int s) {
    __syncthreads();
    if (threadIdx.x == 0) {
        __threadfence();
        unsigned arr = atomicAdd(&bar[s], 1u) + 1u;
        if (arr < (unsigned)NBLK)
            while (atomicAdd(&bar[s], 0u) < (unsigned)NBLK)
                __builtin_amdgcn_s_sleep(2);
        __threadfence();
    }
    __syncthreads();
}

// =====================  FUSED PIPELINE (fast path)  =====================
__global__ __launch_bounds__(NTHR) void k_fused(const float* __restrict__ cls,
                                                const float* __restrict__ loc,
                                                const float* __restrict__ anc,
                                                unsigned* __restrict__ hist,
                                                unsigned* __restrict__ meta,
                                                ull* __restrict__ vmask,
                                                unsigned* __restrict__ rank,
                                                ull* __restrict__ cand,
                                                float4* __restrict__ topbox,
                                                ull* __restrict__ supp,
                                                unsigned* __restrict__ bar,
                                                float* __restrict__ out, int n) {
    __shared__ __align__(16) ull smem8[6400];   // 51.2 KB, re-purposed per phase
    __shared__ unsigned sword;
    __shared__ int snk;
    const int tid = threadIdx.x, bid = blockIdx.x;
    const int wid = tid >> 6, lane = tid & 63;
    const int stride = NBLK * NTHR;
    const int iters = (n + stride - 1) / stride;

    // ---- P1: per-block LDS histogram ----
    {
        unsigned* lh = (unsigned*)smem8;        // 32 KB
        for (int q = tid; q < NBUCK; q += NTHR) lh[q] = 0u;
        __syncthreads();
        for (int it = 0; it < iters; it++) {
            int i = bid * NTHR + tid + it * stride;
            if (i < n) {
                unsigned u = make_key(cls, loc, anc, i);
                atomicAdd(&lh[u >> BSHIFT], 1u);
            }
        }
        __syncthreads();
        for (int qq = 0; qq < NBUCK / NTHR; qq++) {
            int q = (qq + bid) & (NBUCK / NTHR - 1);   // stagger
            int b = q * NTHR + tid;
            unsigned v = lh[b];
            if (v) atomicAdd(&hist[b], v);
        }
    }
    gsync(bar, 0);

    // ---- P2: boundary bucket (block 0) ----
    if (bid == 0) {
        unsigned* ps = (unsigned*)smem8;
        int base = tid * (NBUCK / NTHR);
        unsigned local = 0;
        for (int b = 0; b < NBUCK / NTHR; b++) local += hist[base + b];
        ps[tid] = local;
        __syncthreads();
        for (int off = 1; off < NTHR; off <<= 1) {
            unsigned add = (tid + off < NTHR) ? ps[tid + off] : 0u;
            __syncthreads();
            ps[tid] += add;
            __syncthreads();
        }
        unsigned incl = ps[tid], excl = incl - local;
        if (incl >= (unsigned)PRE_NMS && excl < (unsigned)PRE_NMS) {
            unsigned cum = excl; int B = base;
            for (int b = NBUCK / NTHR - 1; b >= 0; b--) {
                cum += hist[base + b];
                if (cum >= (unsigned)PRE_NMS) { B = base + b; break; }
            }
            meta[0] = (unsigned)B;
        }
    }
    gsync(bar, 1);

    // ---- P3: compact (recompute keys; wave-aggregated push) ----
    if (tid == 0) sword = meta[0];
    __syncthreads();
    {
        unsigned B = sword;
        for (int it = 0; it < iters; it++) {
            int i = bid * NTHR + tid + it * stride;
            unsigned u = 0u;
            if (i < n) u = make_key(cls, loc, anc, i);
            bool pred = (i < n) && ((u >> BSHIFT) >= B);
            ull mask = __ballot(pred);
            if (mask) {
                int leader = __builtin_ctzll(mask);
                unsigned basep = 0;
                if (lane == leader) basep = atomicAdd(&meta[1], (unsigned)__popcll(mask));
                basep = (unsigned)__shfl((int)basep, leader, 64);
                if (pred) {
                    unsigned p = basep + (unsigned)__popcll(mask & ((1ull << lane) - 1ull));
                    if (p < CAP) cand[p] = ((ull)(~u) << 32) | (unsigned)i;
                }
            }
        }
    }
    gsync(bar, 2);

    // ---- P4: exact rank by counting (v-block bx=bid>>5, by=bid&31) ----
    if (tid == 0) sword = meta[1];
    __syncthreads();
    unsigned C = sword; if (C > CAP) C = CAP;
    {
        ull* tile = smem8;
        int bx = bid >> 5, by = bid & 31;
        int ibase = bx * NTHR * RITEMS;
        ull ki[RITEMS]; unsigned cnt[RITEMS];
        #pragma unroll
        for (int r = 0; r < RITEMS; r++) {
            int i = ibase + r * NTHR + tid;
            ki[r] = (i < (int)C) ? cand[i] : ~0ull;
            cnt[r] = 0u;
        }
        int j = by * RTILE + tid;
        tile[tid] = (j < (int)C) ? cand[j] : ~0ull;
        __syncthreads();
        const ulonglong2* t2 = (const ulonglong2*)tile;
        for (int q = 0; q < RTILE / 2; q++) {
            ulonglong2 v = t2[q];
            #pragma unroll
            for (int r = 0; r < RITEMS; r++)
                cnt[r] += (unsigned)(v.x < ki[r]) + (unsigned)(v.y < ki[r]);
        }
        #pragma unroll
        for (int r = 0; r < RITEMS; r++)
            if (cnt[r]) atomicAdd(&rank[ibase + r * NTHR + tid], cnt[r]);
    }
    gsync(bar, 3);

    // ---- P5: scatter + decode (blocks 0..31) ----
    if (bid < CAP / NTHR) {
        int i = bid * NTHR + tid;
        if (i < (int)C) {
            ull kv = cand[i];
            unsigned uu = ~(unsigned)(kv >> 32);
            if (uu != 0u) {
                unsigned r = rank[i];
                if (r < PRE_NMS) {
                    int idx = (int)(unsigned)kv;
                    topbox[r] = decode_box(loc, anc, idx);
                    atomicOr(&vmask[r >> 6], 1ull << (r & 63));
                }
            }
        }
    }
    gsync(bar, 4);

    // ---- P6: suppression bitmask, upper-tri 64x64 v-blocks ----
    // topbox slots never scattered hold poison; their rows/cols are never
    // kept (vmask=0) so garbage bits are harmless. No lower-tri zero-fill:
    // scan merges pollute only already-consumed state words.
    {
        float4* cb4 = ((float4*)smem8) + wid * 64;   // per-wave slice, no barrier
        int gw = bid * 4 + wid;
        for (int vb = gw; vb < KW * KW; vb += NBLK * 4) {
            int rb = vb / KW, cb = vb - rb * KW;
            if (cb < rb) continue;
            int jt = cb * 64 + lane;
            cb4[lane] = (jt < PRE_NMS) ? topbox[jt] : make_float4(3.f, 3.f, 3.f, 3.f);
            int i = rb * 64 + lane;
            if (i < PRE_NMS) {
                float4 bi = topbox[i];
                float ai = (bi.z - bi.x) * (bi.w - bi.y);
                ull bits = 0ull;
                int j0 = cb * 64;
                for (int jj = 0; jj < 64; jj++) {
                    int j = j0 + jj;
                    if (j <= i || j >= PRE_NMS) continue;
                    float4 bj = cb4[jj];
                    float aj = (bj.z - bj.x) * (bj.w - bj.y);
                    float lx = fmaxf(bi.x, bj.x), ly = fmaxf(bi.y, bj.y);
                    float rx = fminf(bi.z, bj.z), ry = fminf(bi.w, bj.w);
                    float iw = fmaxf(rx - lx, 0.f), ih = fmaxf(ry - ly, 0.f);
                    float inter = iw * ih;
                    float iou = inter / (ai + aj - inter + 1e-12f);
                    if (iou > IOU_TH) bits |= (1ull << jj);
                }
                supp[(size_t)i * KW + cb] = bits;
            }
        }
    }
    gsync(bar, 5);

    // ---- P7: chunked greedy scan (block 0) ----
    if (bid == 0) {
        ull* dg  = smem8;                      // 94 chunks x 64 diag words (47 KB)
        ull* vml = smem8 + KW * 64;            // 94
        int* klist = (int*)(smem8 + KW * 64 + KW);   // 300 ints
        for (int q = tid; q < KW * 64; q += NTHR) {
            int c = q >> 6, l2 = q & 63;
            int row = c * 64 + l2;
            dg[q] = (row < PRE_NMS) ? supp[(size_t)row * KW + c] : 0ull;
        }
        for (int q = tid; q < KW; q += NTHR) vml[q] = vmask[q];
        __syncthreads();
        if (wid == 0) {
            ull r0 = 0ull, r1 = 0ull;
            int nk = 0;
            bool done = false;
            for (int c = 0; c < KW && !done; c++) {
                ull dw = dg[c * 64 + lane];            // my row's diag word
                ull st = (c < 64) ? bcast64(r0, c) : bcast64(r1, c - 64);
                ull todo = ~st & vml[c];
                ull kept = 0ull;
                while (todo) {                          // resolve: shfl/ALU only
                    int b = __builtin_ctzll(todo);
                    kept |= 1ull << b;
                    if (lane == 0) klist[nk] = c * 64 + b;
                    nk++;
                    if (nk == POST_NMS) { done = true; break; }
                    ull wb = bcast64(dw, b);
                    todo &= ~wb;
                    todo &= ~(1ull << b);
                }
                if (done) { if (lane == 0) snk = nk; break; }
                while (kept) {                          // batch-merge kept rows (4-wide)
                    int b0 = __builtin_ctzll(kept); kept &= kept - 1ull;
                    int b1 = -1, b2 = -1, b3 = -1;
                    if (kept) { b1 = __builtin_ctzll(kept); kept &= kept - 1ull; }
                    if (kept) { b2 = __builtin_ctzll(kept); kept &= kept - 1ull; }
                    if (kept) { b3 = __builtin_ctzll(kept); kept &= kept - 1ull; }
                    const ull* p0 = supp + (size_t)(c * 64 + b0) * KW;
                    ull a0 = p0[lane], h0 = (lane < KW - 64) ? p0[64 + lane] : 0ull;
                    ull a1 = 0, h1 = 0, a2 = 0, h2 = 0, a3 = 0, h3 = 0;
                    if (b1 >= 0) { const ull* p = supp + (size_t)(c * 64 + b1) * KW;
                                   a1 = p[lane]; h1 = (lane < KW - 64) ? p[64 + lane] : 0ull; }
                    if (b2 >= 0) { const ull* p = supp + (size_t)(c * 64 + b2) * KW;
                                   a2 = p[lane]; h2 = (lane < KW - 64) ? p[64 + lane] : 0ull; }
                    if (b3 >= 0) { const ull* p = supp + (size_t)(c * 64 + b3) * KW;
                                   a3 = p[lane]; h3 = (lane < KW - 64) ? p[64 + lane] : 0ull; }
                    r0 |= a0 | a1 | a2 | a3;
                    r1 |= h0 | h1 | h2 | h3;
                }
            }
            if (lane == 0) snk = nk;
        }
        __syncthreads();
        int nk = snk;
        for (int q = tid; q < POST_NMS; q += NTHR)
            ((float4*)out)[q] = (q < nk) ? topbox[klist[q]]
                                         : make_float4(0.f, 0.f, 0.f, 0.f);
    }
}

// =====================  small-ws fallback (R5-validated)  ================
__global__ __launch_bounds__(256) void k_score(const float* __restrict__ cls,
                                               const float* __restrict__ loc,
                                               const float* __restrict__ anc,
                                               unsigned* __restrict__ hist, int n) {
    __shared__ unsigned lh[NBUCK];
    int tid = threadIdx.x, bid = blockIdx.x;
    for (int q = tid; q < NBUCK; q += 256) lh[q] = 0u;
    __syncthreads();
    for (int i = bid * 256 + tid; i < n; i += SBLK * 256) {
        unsigned u = make_key(cls, loc, anc, i);
        atomicAdd(&lh[u >> BSHIFT], 1u);
    }
    __syncthreads();
    for (int qq = 0; qq < NBUCK / 256; qq++) {
        int q = (qq + bid) & (NBUCK / 256 - 1);
        int b = q * 256 + tid;
        unsigned v = lh[b];
        if (v) atomicAdd(&hist[b], v);
    }
}

__global__ __launch_bounds__(1024) void k_findb(const unsigned* __restrict__ hist,
                                                unsigned* __restrict__ meta) {
    __shared__ unsigned ps[1024];
    int t = threadIdx.x;
    int base = t * (NBUCK / 1024);
    unsigned local = 0;
    for (int b = 0; b < NBUCK / 1024; b++) local += hist[base + b];
    ps[t] = local;
    __syncthreads();
    for (int off = 1; off < 1024; off <<= 1) {
        unsigned add = (t + off < 1024) ? ps[t + off] : 0u;
        __syncthreads();
        ps[t] += add;
        __syncthreads();
    }
    unsigned incl = ps[t], excl = incl - local;
    if (incl >= (unsigned)PRE_NMS && excl < (unsigned)PRE_NMS) {
        unsigned cum = excl; int B = base;
        for (int b = NBUCK / 1024 - 1; b >= 0; b--) {
            cum += hist[base + b];
            if (cum >= (unsigned)PRE_NMS) { B = base + b; break; }
        }
        meta[0] = (unsigned)B;
    }
}

__global__ __launch_bounds__(256) void k_compactR(const float* __restrict__ cls,
                                                  const float* __restrict__ loc,
                                                  const float* __restrict__ anc,
                                                  unsigned* __restrict__ meta,
                                                  ull* __restrict__ cand, int n) {
    int i = blockIdx.x * blockDim.x + threadIdx.x;
    if (i >= n) return;
    unsigned u = make_key(cls, loc, anc, i);
    if ((u >> BSHIFT) >= meta[0]) {
        unsigned p = atomicAdd(&meta[1], 1u);
        if (p < CAP) cand[p] = ((ull)(~u) << 32) | (unsigned)i;
    }
}

__global__ __launch_bounds__(256) void k_rank(const ull* __restrict__ cand,
                                              const unsigned* __restrict__ meta,
                                              unsigned* __restrict__ rank,
                                              float4* __restrict__ topbox) {
    __shared__ __align__(16) ull tile[RTILE];
    int tid = threadIdx.x;
    int bx = blockIdx.x, by = blockIdx.y;
    unsigned C = meta[1]; if (C > CAP) C = CAP;
    if (by == 0) {
        int per = TB_PAD / (CAP / (256 * RITEMS));
        int s0 = bx * per;
        for (int q = tid; q < per; q += 256)
            topbox[s0 + q] = make_float4(-1.f, -1.f, -1.f, -1.f);
    }
    int ibase = bx * 256 * RITEMS;
    ull ki[RITEMS]; unsigned cnt[RITEMS];
    #pragma unroll
    for (int r = 0; r < RITEMS; r++) {
        int i = ibase + r * 256 + tid;
        ki[r] = (i < (int)C) ? cand[i] : ~0ull;
        cnt[r] = 0u;
    }
    int j = by * RTILE + tid;
    tile[tid] = (j < (int)C) ? cand[j] : ~0ull;
    __syncthreads();
    const ulonglong2* t2 = (const ulonglong2*)tile;
    for (int q = 0; q < RTILE / 2; q++) {
        ulonglong2 v = t2[q];
        #pragma unroll
        for (int r = 0; r < RITEMS; r++)
            cnt[r] += (unsigned)(v.x < ki[r]) + (unsigned)(v.y < ki[r]);
    }
    #pragma unroll
    for (int r = 0; r < RITEMS; r++)
        if (cnt[r]) atomicAdd(&rank[ibase + r * 256 + tid], cnt[r]);
}

__global__ __launch_bounds__(256) void k_scatter(const ull* __restrict__ cand,
                                                 const unsigned* __restrict__ meta,
                                                 const unsigned* __restrict__ rank,
                                                 const float* __restrict__ loc,
                                                 const float* __restrict__ anc,
                                                 float4* __restrict__ topbox,
                                                 ull* __restrict__ vmask) {
    int i = blockIdx.x * 256 + threadIdx.x;
    unsigned C = meta[1]; if (C > CAP) C = CAP;
    if (i >= (int)C) return;
    ull kv = cand[i];
    unsigned uu = ~(unsigned)(kv >> 32);
    if (uu == 0u) return;
    unsigned r = rank[i];
    if (r >= PRE_NMS) return;
    int idx = (int)(unsigned)kv;
    topbox[r] = decode_box(loc, anc, idx);
    atomicOr(&vmask[r >> 6], 1ull << (r & 63));
}

__global__ __launch_bounds__(64) void k_nms(const float4* __restrict__ topbox,
                                            float* __restrict__ out) {
    int l = threadIdx.x;
    float4 kb[5];
    int nk = 0;
    for (int q0 = 0; q0 < TB_PAD && nk < POST_NMS; q0 += 64) {
        float4 myb = topbox[q0 + l];
        for (int b = 0; b < 64 && nk < POST_NMS; b++) {
            float4 bb;
            bb.x = __shfl(myb.x, b, 64);
            bb.y = __shfl(myb.y, b, 64);
            bb.z = __shfl(myb.z, b, 64);
            bb.w = __shfl(myb.w, b, 64);
            if (bb.x < 0.f) continue;
            float ab = (bb.z - bb.x) * (bb.w - bb.y);
            bool sup = false;
            #pragma unroll
            for (int r = 0; r < 5; r++) {
                int s = r * 64 + l;
                if (s < nk) {
                    float4 kv = kb[r];
                    float ak = (kv.z - kv.x) * (kv.w - kv.y);
                    float lx = fmaxf(bb.x, kv.x), ly = fmaxf(bb.y, kv.y);
                    float rx = fminf(bb.z, kv.z), ry = fminf(bb.w, kv.w);
                    float iw = fmaxf(rx - lx, 0.f), ih = fmaxf(ry - ly, 0.f);
                    float inter = iw * ih;
                    float iou = inter / (ab + ak - inter + 1e-12f);
                    sup |= (iou > IOU_TH);
                }
            }
            if (!__any(sup)) {
                if (l == (nk & 63)) kb[nk >> 6] = bb;
                if (l < 4) {
                    float v = (l == 0) ? bb.x : (l == 1) ? bb.y : (l == 2) ? bb.z : bb.w;
                    out[4 * nk + l] = v;
                }
                nk++;
            }
        }
    }
    for (int t = nk * 4 + l; t < POST_NMS * 4; t += 64) out[t] = 0.f;
}

extern "C" void kernel_launch(void* const* d_in, const int* in_sizes, int n_in,
                              void* d_out, int out_size, void* d_ws, size_t ws_size,
                              hipStream_t stream) {
    const int N = in_sizes[0] / 2;             // 202500
    const float* cls = (const float*)d_in[0];
    const float* loc = (const float*)d_in[1];
    const float* anc = (const float*)d_in[2];
    float* out = (float*)d_out;

    char* ws = (char*)d_ws;
    size_t off = 0;
    auto take = [&](size_t bytes) {
        size_t o = off;
        off += (bytes + 255) & ~(size_t)255;
        return o;
    };
    // zero region (one memset): hist + meta/bar/vmask + rank
    unsigned* hist = (unsigned*)(ws + take((size_t)NBUCK * 4));      // 32 KB
    char*     mblk = ws + take(1024);
    unsigned* meta  = (unsigned*)mblk;                               // [0..15]
    unsigned* bar   = (unsigned*)(mblk + 64);                        // 16 slots
    ull*      vmask = (ull*)(mblk + 256);                            // 94 words
    unsigned* rank = (unsigned*)(ws + take((size_t)CAP * 4));        // 32 KB
    size_t zlen = off;
    ull*    cand   = (ull*)(ws + take((size_t)CAP * 8));             // 64 KB
    float4* topbox = (float4*)(ws + take((size_t)TB_PAD * 16));      // 94 KB
    ull*    supp   = (ull*)(ws + take((size_t)PRE_NMS * KW * 8));    // 4.42 MB
    size_t full_need = off;
    const bool fast = (ws_size >= full_need);   // constant across calls

    hipMemsetAsync(ws, 0, zlen, stream);

    if (fast) {
        k_fused<<<NBLK, NTHR, 0, stream>>>(cls, loc, anc, hist, meta, vmask,
                                           rank, cand, topbox, supp, bar, out, N);
    } else {
        dim3 rgrid(CAP / (256 * RITEMS), CAP / RTILE);
        k_score<<<SBLK, 256, 0, stream>>>(cls, loc, anc, hist, N);
        k_findb<<<1, 1024, 0, stream>>>(hist, meta);
        k_compactR<<<(N + 255) / 256, 256, 0, stream>>>(cls, loc, anc, meta, cand, N);
        k_rank<<<rgrid, 256, 0, stream>>>(cand, meta, rank, topbox);
        k_scatter<<<CAP / 256, 256, 0, stream>>>(cand, meta, rank, loc, anc, topbox, vmask);
        k_nms<<<1, 64, 0, stream>>>(topbox, out);
    }
}

// Round 7
// 340.566 us; speedup vs baseline: 1.0247x; 1.0247x over previous
//
#include <hip/hip_runtime.h>
#include <hip/hip_bf16.h>

#define NANCH 202500
#define PRE_NMS 6000
#define POST_NMS 300
#define KW 94            // ceil(6016/64) words per supp row
#define CAP 8192
#define NBUCK 16384
#define BSHIFT 18
#define IOU_TH 0.7f
#define MIN_SIZE 0.016f
#define TB_PAD 6016
#define RITEMS 8
#define RTILE 256
#define SBLK 256         // k1 grid blocks

typedef unsigned long long ull;

// ---------------- shared decode / key helpers ---------------------------
__device__ inline float4 decode_box(const float* __restrict__ loc,
                                    const float* __restrict__ anc, int i) {
    float4 a = ((const float4*)anc)[i];
    float4 t = ((const float4*)loc)[i];
    float pw = a.z - a.x, ph = a.w - a.y;
    float pcx = (a.x + a.z) * 0.5f, pcy = (a.y + a.w) * 0.5f;
    float cx = t.x * pw + pcx, cy = t.y * ph + pcy;
    float w = expf(t.z) * pw, h = expf(t.w) * ph;
    float x1 = fminf(fmaxf(cx - 0.5f * w, 0.f), 1.f);
    float y1 = fminf(fmaxf(cy - 0.5f * h, 0.f), 1.f);
    float x2 = fminf(fmaxf(cx + 0.5f * w, 0.f), 1.f);
    float y2 = fminf(fmaxf(cy + 0.5f * h, 0.f), 1.f);
    return make_float4(x1, y1, x2, y2);
}

__device__ inline unsigned make_key(const float* __restrict__ cls,
                                    const float* __restrict__ loc,
                                    const float* __restrict__ anc, int i) {
    float2 c = ((const float2*)cls)[i];
    float d = c.y - c.x;                       // monotone proxy for softmax[:,1]
    float4 b = decode_box(loc, anc, i);
    bool valid = ((b.z - b.x) >= MIN_SIZE) && ((b.w - b.y) >= MIN_SIZE);
    unsigned ib = __float_as_uint(d);
    unsigned u = (ib & 0x80000000u) ? ~ib : (ib | 0x80000000u);  // monotonic key
    return valid ? u : 0u;
}

__device__ inline ull bcast64(ull v, int lane) {
    unsigned lo = (unsigned)v, hi = (unsigned)(v >> 32);
    lo = (unsigned)__shfl((int)lo, lane, 64);
    hi = (unsigned)__shfl((int)hi, lane, 64);
    return ((ull)hi << 32) | lo;
}

// ============ K1: keys + LDS histogram; LAST block finds boundary ========
__global__ __launch_bounds__(256) void k_score_fb(const float* __restrict__ cls,
                                                  const float* __restrict__ loc,
                                                  const float* __restrict__ anc,
                                                  unsigned* __restrict__ hist,
                                                  unsigned* __restrict__ keyc,
                                                  unsigned* __restrict__ meta, int n) {
    __shared__ unsigned lh[NBUCK];             // 64 KB
    __shared__ int slast;
    int tid = threadIdx.x, bid = blockIdx.x;
    for (int q = tid; q < NBUCK; q += 256) lh[q] = 0u;
    __syncthreads();
    for (int i = bid * 256 + tid; i < n; i += SBLK * 256) {
        unsigned u = make_key(cls, loc, anc, i);
        keyc[i] = u;
        atomicAdd(&lh[u >> BSHIFT], 1u);
    }
    __syncthreads();
    for (int qq = 0; qq < NBUCK / 256; qq++) {
        int q = (qq + bid) & (NBUCK / 256 - 1);     // stagger across blocks
        int b = q * 256 + tid;
        unsigned v = lh[b];
        if (v) atomicAdd(&hist[b], v);
    }
    // ticket: last block to finish does findb (no spinning)
    __syncthreads();
    if (tid == 0) {
        __threadfence();                        // release our flush
        slast = (atomicAdd(&meta[2], 1u) == (unsigned)(SBLK - 1));
    }
    __syncthreads();
    if (!slast) return;
    __threadfence();                            // acquire others' flushes
    unsigned* ps = lh;                          // reuse LDS
    int base = tid * (NBUCK / 256);
    unsigned local = 0;
    for (int b = 0; b < NBUCK / 256; b++) local += hist[base + b];
    __syncthreads();
    ps[tid] = local;
    __syncthreads();
    for (int off = 1; off < 256; off <<= 1) {   // suffix-inclusive scan
        unsigned add = (tid + off < 256) ? ps[tid + off] : 0u;
        __syncthreads();
        ps[tid] += add;
        __syncthreads();
    }
    unsigned incl = ps[tid], excl = incl - local;
    if (incl >= (unsigned)PRE_NMS && excl < (unsigned)PRE_NMS) {
        unsigned cum = excl; int B = base;
        for (int b = NBUCK / 256 - 1; b >= 0; b--) {
            cum += hist[base + b];
            if (cum >= (unsigned)PRE_NMS) { B = base + b; break; }
        }
        meta[0] = (unsigned)B;
    }
}

// ============ K2: compact (cached keys, wave-aggregated atomic) ==========
__global__ __launch_bounds__(256) void k_compactC(const unsigned* __restrict__ keyc,
                                                  unsigned* __restrict__ meta,
                                                  ull* __restrict__ cand, int n) {
    int i = blockIdx.x * blockDim.x + threadIdx.x;
    unsigned u = (i < n) ? keyc[i] : 0u;
    unsigned B = meta[0];
    bool pred = (i < n) && ((u >> BSHIFT) >= B);
    ull mask = __ballot(pred);
    if (!mask) return;
    int lane = threadIdx.x & 63;
    int leader = __builtin_ctzll(mask);
    unsigned base = 0;
    if (lane == leader) base = atomicAdd(&meta[1], (unsigned)__popcll(mask));
    base = (unsigned)__shfl((int)base, leader, 64);
    if (pred) {
        unsigned p = base + (unsigned)__popcll(mask & ((1ull << lane) - 1ull));
        if (p < CAP) cand[p] = ((ull)(~u) << 32) | (unsigned)i;
    }
}

// ============ K3: exact rank; LAST block scatters + decodes ==============
__global__ __launch_bounds__(256) void k_rank_sc(const ull* __restrict__ cand,
                                                 unsigned* __restrict__ meta,
                                                 unsigned* __restrict__ rank,
                                                 const float* __restrict__ loc,
                                                 const float* __restrict__ anc,
                                                 float4* __restrict__ topbox,
                                                 ull* __restrict__ vmask) {
    __shared__ __align__(16) ull tile[RTILE];
    __shared__ int slast;
    int tid = threadIdx.x;
    int bx = blockIdx.x, by = blockIdx.y;
    unsigned C = meta[1]; if (C > CAP) C = CAP;
    int ibase = bx * 256 * RITEMS;
    ull ki[RITEMS]; unsigned cnt[RITEMS];
    #pragma unroll
    for (int r = 0; r < RITEMS; r++) {
        int i = ibase + r * 256 + tid;
        ki[r] = (i < (int)C) ? cand[i] : ~0ull;
        cnt[r] = 0u;
    }
    int j = by * RTILE + tid;
    tile[tid] = (j < (int)C) ? cand[j] : ~0ull;   // pad = +inf
    __syncthreads();
    const ulonglong2* t2 = (const ulonglong2*)tile;
    for (int q = 0; q < RTILE / 2; q++) {
        ulonglong2 v = t2[q];
        #pragma unroll
        for (int r = 0; r < RITEMS; r++)
            cnt[r] += (unsigned)(v.x < ki[r]) + (unsigned)(v.y < ki[r]);
    }
    #pragma unroll
    for (int r = 0; r < RITEMS; r++)
        if (cnt[r]) atomicAdd(&rank[ibase + r * 256 + tid], cnt[r]);
    // ticket: last of the 128 blocks scatters
    __syncthreads();
    if (tid == 0) {
        __threadfence();
        slast = (atomicAdd(&meta[3], 1u) == gridDim.x * gridDim.y - 1);
    }
    __syncthreads();
    if (!slast) return;
    __threadfence();
    for (int i = tid; i < (int)C; i += 256) {
        ull kv = cand[i];
        unsigned uu = ~(unsigned)(kv >> 32);
        if (uu == 0u) continue;                // invalid box
        unsigned r = rank[i];
        if (r >= PRE_NMS) continue;            // outside top-6000
        int idx = (int)(unsigned)kv;
        topbox[r] = decode_box(loc, anc, idx);
        atomicOr(&vmask[r >> 6], 1ull << (r & 63));
    }
}

// ============ K4: suppression matrix; LAST block runs chunked scan =======
// grid = KW*KW/4 blocks x 256 (one 64x64 tile per wave, full-device parallel).
// Lower-tri tiles skipped entirely (scan merges touch only already-consumed
// state words -> garbage harmless; validated in R6).
__global__ __launch_bounds__(256) void k_supp_scan(const float4* __restrict__ topbox,
                                                   ull* __restrict__ supp,
                                                   unsigned* __restrict__ meta,
                                                   const ull* __restrict__ vmask,
                                                   float* __restrict__ out) {
    __shared__ __align__(16) ull smem[6272];   // 50.2 KB (scan); supp uses 4 KB
    __shared__ int slast, snk;
    int tid = threadIdx.x, bid = blockIdx.x;
    int wid = tid >> 6, lane = tid & 63;
    // ---- supp phase: one upper-tri tile per wave ----
    {
        float4* cb4 = ((float4*)smem) + wid * 64;
        int vb = bid * 4 + wid;
        if (vb < KW * KW) {
            int rb = vb / KW, cb = vb - rb * KW;
            if (cb >= rb) {
                int jt = cb * 64 + lane;
                cb4[lane] = (jt < PRE_NMS) ? topbox[jt] : make_float4(3.f, 3.f, 3.f, 3.f);
                int i = rb * 64 + lane;
                if (i < PRE_NMS) {
                    float4 bi = topbox[i];
                    float ai = (bi.z - bi.x) * (bi.w - bi.y);
                    ull bits = 0ull;
                    int j0 = cb * 64;
                    for (int jj = 0; jj < 64; jj++) {
                        int j = j0 + jj;
                        if (j <= i || j >= PRE_NMS) continue;
                        float4 bj = cb4[jj];
                        float aj = (bj.z - bj.x) * (bj.w - bj.y);
                        float lx = fmaxf(bi.x, bj.x), ly = fmaxf(bi.y, bj.y);
                        float rx = fminf(bi.z, bj.z), ry = fminf(bi.w, bj.w);
                        float iw = fmaxf(rx - lx, 0.f), ih = fmaxf(ry - ly, 0.f);
                        float inter = iw * ih;
                        float iou = inter / (ai + aj - inter + 1e-12f);
                        if (iou > IOU_TH) bits |= (1ull << jj);
                    }
                    supp[(size_t)i * KW + cb] = bits;
                }
            }
        }
    }
    __syncthreads();
    if (tid == 0) {
        __threadfence();
        slast = (atomicAdd(&meta[4], 1u) == gridDim.x - 1);
    }
    __syncthreads();
    if (!slast) return;
    __threadfence();
    // ---- scan phase (last block only) ----
    ull* dg  = smem;                           // 94 chunks x 64 diag words
    ull* vml = smem + KW * 64;                 // 94 words
    int* klist = (int*)(smem + KW * 64 + KW);  // 300 ints
    for (int q = tid; q < KW * 64; q += 256) {
        int c = q >> 6, l2 = q & 63;
        int row = c * 64 + l2;
        dg[q] = (row < PRE_NMS) ? supp[(size_t)row * KW + c] : 0ull;
    }
    for (int q = tid; q < KW; q += 256) vml[q] = vmask[q];
    __syncthreads();
    if (wid == 0) {
        ull r0 = 0ull, r1 = 0ull;
        int nk = 0;
        bool done = false;
        for (int c = 0; c < KW && !done; c++) {
            ull dw = dg[c * 64 + lane];        // my row's diag word
            ull st = (c < 64) ? bcast64(r0, c) : bcast64(r1, c - 64);
            ull todo = ~st & vml[c];
            ull kept = 0ull;
            while (todo) {                     // resolve chunk: shfl/ALU only
                int b = __builtin_ctzll(todo);
                kept |= 1ull << b;
                if (lane == 0) klist[nk] = c * 64 + b;
                nk++;
                if (nk == POST_NMS) { done = true; break; }
                ull wb = bcast64(dw, b);
                todo &= ~wb;
                todo &= ~(1ull << b);
            }
            if (done) break;
            while (kept) {                     // batch-merge kept rows, 4-wide
                int b0 = __builtin_ctzll(kept); kept &= kept - 1ull;
                int b1 = -1, b2 = -1, b3 = -1;
                if (kept) { b1 = __builtin_ctzll(kept); kept &= kept - 1ull; }
                if (kept) { b2 = __builtin_ctzll(kept); kept &= kept - 1ull; }
                if (kept) { b3 = __builtin_ctzll(kept); kept &= kept - 1ull; }
                const ull* p0 = supp + (size_t)(c * 64 + b0) * KW;
                ull a0 = p0[lane], h0 = (lane < KW - 64) ? p0[64 + lane] : 0ull;
                ull a1 = 0, h1 = 0, a2 = 0, h2 = 0, a3 = 0, h3 = 0;
                if (b1 >= 0) { const ull* p = supp + (size_t)(c * 64 + b1) * KW;
                               a1 = p[lane]; h1 = (lane < KW - 64) ? p[64 + lane] : 0ull; }
                if (b2 >= 0) { const ull* p = supp + (size_t)(c * 64 + b2) * KW;
                               a2 = p[lane]; h2 = (lane < KW - 64) ? p[64 + lane] : 0ull; }
                if (b3 >= 0) { const ull* p = supp + (size_t)(c * 64 + b3) * KW;
                               a3 = p[lane]; h3 = (lane < KW - 64) ? p[64 + lane] : 0ull; }
                r0 |= a0 | a1 | a2 | a3;
                r1 |= h0 | h1 | h2 | h3;
            }
        }
        if (lane == 0) snk = nk;
    }
    __syncthreads();
    int nk = snk;
    for (int q = tid; q < POST_NMS; q += 256)
        ((float4*)out)[q] = (q < nk) ? topbox[klist[q]]
                                     : make_float4(0.f, 0.f, 0.f, 0.f);
}

// =====================  small-ws fallback (R5-validated)  ================
__global__ __launch_bounds__(256) void k_score(const float* __restrict__ cls,
                                               const float* __restrict__ loc,
                                               const float* __restrict__ anc,
                                               unsigned* __restrict__ hist, int n) {
    __shared__ unsigned lh[NBUCK];
    int tid = threadIdx.x, bid = blockIdx.x;
    for (int q = tid; q < NBUCK; q += 256) lh[q] = 0u;
    __syncthreads();
    for (int i = bid * 256 + tid; i < n; i += SBLK * 256) {
        unsigned u = make_key(cls, loc, anc, i);
        atomicAdd(&lh[u >> BSHIFT], 1u);
    }
    __syncthreads();
    for (int qq = 0; qq < NBUCK / 256; qq++) {
        int q = (qq + bid) & (NBUCK / 256 - 1);
        int b = q * 256 + tid;
        unsigned v = lh[b];
        if (v) atomicAdd(&hist[b], v);
    }
}

__global__ __launch_bounds__(1024) void k_findb(const unsigned* __restrict__ hist,
                                                unsigned* __restrict__ meta) {
    __shared__ unsigned ps[1024];
    int t = threadIdx.x;
    int base = t * (NBUCK / 1024);
    unsigned local = 0;
    for (int b = 0; b < NBUCK / 1024; b++) local += hist[base + b];
    ps[t] = local;
    __syncthreads();
    for (int off = 1; off < 1024; off <<= 1) {
        unsigned add = (t + off < 1024) ? ps[t + off] : 0u;
        __syncthreads();
        ps[t] += add;
        __syncthreads();
    }
    unsigned incl = ps[t], excl = incl - local;
    if (incl >= (unsigned)PRE_NMS && excl < (unsigned)PRE_NMS) {
        unsigned cum = excl; int B = base;
        for (int b = NBUCK / 1024 - 1; b >= 0; b--) {
            cum += hist[base + b];
            if (cum >= (unsigned)PRE_NMS) { B = base + b; break; }
        }
        meta[0] = (unsigned)B;
    }
}

__global__ __launch_bounds__(256) void k_compactR(const float* __restrict__ cls,
                                                  const float* __restrict__ loc,
                                                  const float* __restrict__ anc,
                                                  unsigned* __restrict__ meta,
                                                  ull* __restrict__ cand, int n) {
    int i = blockIdx.x * blockDim.x + threadIdx.x;
    if (i >= n) return;
    unsigned u = make_key(cls, loc, anc, i);
    if ((u >> BSHIFT) >= meta[0]) {
        unsigned p = atomicAdd(&meta[1], 1u);
        if (p < CAP) cand[p] = ((ull)(~u) << 32) | (unsigned)i;
    }
}

__global__ __launch_bounds__(256) void k_rank(const ull* __restrict__ cand,
                                              const unsigned* __restrict__ meta,
                                              unsigned* __restrict__ rank,
                                              float4* __restrict__ topbox) {
    __shared__ __align__(16) ull tile[RTILE];
    int tid = threadIdx.x;
    int bx = blockIdx.x, by = blockIdx.y;
    unsigned C = meta[1]; if (C > CAP) C = CAP;
    if (by == 0) {
        int per = TB_PAD / (CAP / (256 * RITEMS));
        int s0 = bx * per;
        for (int q = tid; q < per; q += 256)
            topbox[s0 + q] = make_float4(-1.f, -1.f, -1.f, -1.f);
    }
    int ibase = bx * 256 * RITEMS;
    ull ki[RITEMS]; unsigned cnt[RITEMS];
    #pragma unroll
    for (int r = 0; r < RITEMS; r++) {
        int i = ibase + r * 256 + tid;
        ki[r] = (i < (int)C) ? cand[i] : ~0ull;
        cnt[r] = 0u;
    }
    int j = by * RTILE + tid;
    tile[tid] = (j < (int)C) ? cand[j] : ~0ull;
    __syncthreads();
    const ulonglong2* t2 = (const ulonglong2*)tile;
    for (int q = 0; q < RTILE / 2; q++) {
        ulonglong2 v = t2[q];
        #pragma unroll
        for (int r = 0; r < RITEMS; r++)
            cnt[r] += (unsigned)(v.x < ki[r]) + (unsigned)(v.y < ki[r]);
    }
    #pragma unroll
    for (int r = 0; r < RITEMS; r++)
        if (cnt[r]) atomicAdd(&rank[ibase + r * 256 + tid], cnt[r]);
}

__global__ __launch_bounds__(256) void k_scatter(const ull* __restrict__ cand,
                                                 const unsigned* __restrict__ meta,
                                                 const unsigned* __restrict__ rank,
                                                 const float* __restrict__ loc,
                                                 const float* __restrict__ anc,
                                                 float4* __restrict__ topbox,
                                                 ull* __restrict__ vmask) {
    int i = blockIdx.x * 256 + threadIdx.x;
    unsigned C = meta[1]; if (C > CAP) C = CAP;
    if (i >= (int)C) return;
    ull kv = cand[i];
    unsigned uu = ~(unsigned)(kv >> 32);
    if (uu == 0u) return;
    unsigned r = rank[i];
    if (r >= PRE_NMS) return;
    int idx = (int)(unsigned)kv;
    topbox[r] = decode_box(loc, anc, idx);
    atomicOr(&vmask[r >> 6], 1ull << (r & 63));
}

__global__ __launch_bounds__(64) void k_nms(const float4* __restrict__ topbox,
                                            float* __restrict__ out) {
    int l = threadIdx.x;
    float4 kb[5];
    int nk = 0;
    for (int q0 = 0; q0 < TB_PAD && nk < POST_NMS; q0 += 64) {
        float4 myb = topbox[q0 + l];
        for (int b = 0; b < 64 && nk < POST_NMS; b++) {
            float4 bb;
            bb.x = __shfl(myb.x, b, 64);
            bb.y = __shfl(myb.y, b, 64);
            bb.z = __shfl(myb.z, b, 64);
            bb.w = __shfl(myb.w, b, 64);
            if (bb.x < 0.f) continue;
            float ab = (bb.z - bb.x) * (bb.w - bb.y);
            bool sup = false;
            #pragma unroll
            for (int r = 0; r < 5; r++) {
                int s = r * 64 + l;
                if (s < nk) {
                    float4 kv = kb[r];
                    float ak = (kv.z - kv.x) * (kv.w - kv.y);
                    float lx = fmaxf(bb.x, kv.x), ly = fmaxf(bb.y, kv.y);
                    float rx = fminf(bb.z, kv.z), ry = fminf(bb.w, kv.w);
                    float iw = fmaxf(rx - lx, 0.f), ih = fmaxf(ry - ly, 0.f);
                    float inter = iw * ih;
                    float iou = inter / (ab + ak - inter + 1e-12f);
                    sup |= (iou > IOU_TH);
                }
            }
            if (!__any(sup)) {
                if (l == (nk & 63)) kb[nk >> 6] = bb;
                if (l < 4) {
                    float v = (l == 0) ? bb.x : (l == 1) ? bb.y : (l == 2) ? bb.z : bb.w;
                    out[4 * nk + l] = v;
                }
                nk++;
            }
        }
    }
    for (int t = nk * 4 + l; t < POST_NMS * 4; t += 64) out[t] = 0.f;
}

extern "C" void kernel_launch(void* const* d_in, const int* in_sizes, int n_in,
                              void* d_out, int out_size, void* d_ws, size_t ws_size,
                              hipStream_t stream) {
    const int N = in_sizes[0] / 2;             // 202500
    const float* cls = (const float*)d_in[0];
    const float* loc = (const float*)d_in[1];
    const float* anc = (const float*)d_in[2];
    float* out = (float*)d_out;

    char* ws = (char*)d_ws;
    size_t off = 0;
    auto take = [&](size_t bytes) {
        size_t o = off;
        off += (bytes + 255) & ~(size_t)255;
        return o;
    };
    // zero region (one memset): hist + meta/vmask + rank
    unsigned* hist = (unsigned*)(ws + take((size_t)NBUCK * 4));      // 64 KB
    char*     mblk = ws + take(1024);
    unsigned* meta  = (unsigned*)mblk;         // [0]=B [1]=C [2..4]=tickets
    ull*      vmask = (ull*)(mblk + 256);      // 94 words
    unsigned* rank = (unsigned*)(ws + take((size_t)CAP * 4));        // 32 KB
    size_t zlen = off;
    ull*    cand   = (ull*)(ws + take((size_t)CAP * 8));             // 64 KB
    float4* topbox = (float4*)(ws + take((size_t)TB_PAD * 16));      // 94 KB
    unsigned* keyc = (unsigned*)(ws + take((size_t)N * 4));          // 810 KB
    ull*    supp   = (ull*)(ws + take((size_t)PRE_NMS * KW * 8));    // 4.42 MB
    size_t full_need = off;
    const bool fast = (ws_size >= full_need);   // constant across calls

    hipMemsetAsync(ws, 0, zlen, stream);

    if (fast) {
        k_score_fb<<<SBLK, 256, 0, stream>>>(cls, loc, anc, hist, keyc, meta, N);
        k_compactC<<<(N + 255) / 256, 256, 0, stream>>>(keyc, meta, cand, N);
        k_rank_sc<<<dim3(CAP / (256 * RITEMS), CAP / RTILE), 256, 0, stream>>>(
            cand, meta, rank, loc, anc, topbox, vmask);
        k_supp_scan<<<(KW * KW) / 4, 256, 0, stream>>>(topbox, supp, meta, vmask, out);
    } else {
        k_score<<<SBLK, 256, 0, stream>>>(cls, loc, anc, hist, N);
        k_findb<<<1, 1024, 0, stream>>>(hist, meta);
        k_compactR<<<(N + 255) / 256, 256, 0, stream>>>(cls, loc, anc, meta, cand, N);
        k_rank<<<dim3(CAP / (256 * RITEMS), CAP / RTILE), 256, 0, stream>>>(cand, meta, rank, topbox);
        k_scatter<<<CAP / 256, 256, 0, stream>>>(cand, meta, rank, loc, anc, topbox, vmask);
        k_nms<<<1, 64, 0, stream>>>(topbox, out);
    }
}

// Round 8
// 277.466 us; speedup vs baseline: 1.2578x; 1.2274x over previous
//
#include <hip/hip_runtime.h>
#include <hip/hip_bf16.h>

#define NANCH 202500
#define PRE_NMS 6000
#define POST_NMS 300
#define KW 94            // ceil(6016/64) words per supp row
#define CAP 8192
#define NBUCK 16384
#define BSHIFT 18
#define IOU_TH 0.7f
#define MIN_SIZE 0.016f
#define TB_PAD 6016
#define RITEMS 8
#define RTILE 256
#define SBLK 256         // k1 grid blocks

typedef unsigned long long ull;

// ---------------- shared decode / key helpers ---------------------------
__device__ inline float4 decode_box(const float* __restrict__ loc,
                                    const float* __restrict__ anc, int i) {
    float4 a = ((const float4*)anc)[i];
    float4 t = ((const float4*)loc)[i];
    float pw = a.z - a.x, ph = a.w - a.y;
    float pcx = (a.x + a.z) * 0.5f, pcy = (a.y + a.w) * 0.5f;
    float cx = t.x * pw + pcx, cy = t.y * ph + pcy;
    float w = expf(t.z) * pw, h = expf(t.w) * ph;
    float x1 = fminf(fmaxf(cx - 0.5f * w, 0.f), 1.f);
    float y1 = fminf(fmaxf(cy - 0.5f * h, 0.f), 1.f);
    float x2 = fminf(fmaxf(cx + 0.5f * w, 0.f), 1.f);
    float y2 = fminf(fmaxf(cy + 0.5f * h, 0.f), 1.f);
    return make_float4(x1, y1, x2, y2);
}

__device__ inline unsigned make_key(const float* __restrict__ cls,
                                    const float* __restrict__ loc,
                                    const float* __restrict__ anc, int i) {
    float2 c = ((const float2*)cls)[i];
    float d = c.y - c.x;                       // monotone proxy for softmax[:,1]
    float4 b = decode_box(loc, anc, i);
    bool valid = ((b.z - b.x) >= MIN_SIZE) && ((b.w - b.y) >= MIN_SIZE);
    unsigned ib = __float_as_uint(d);
    unsigned u = (ib & 0x80000000u) ? ~ib : (ib | 0x80000000u);  // monotonic key
    return valid ? u : 0u;
}

__device__ inline ull bcast64(ull v, int lane) {
    unsigned lo = (unsigned)v, hi = (unsigned)(v >> 32);
    lo = (unsigned)__shfl((int)lo, lane, 64);
    hi = (unsigned)__shfl((int)hi, lane, 64);
    return ((ull)hi << 32) | lo;
}

// ============ K1: LDS histogram; LAST block finds boundary ==============
// No keyc cache: pre-ticket dirty set = atomic hist only -> release fence
// (vmcnt drain + wbl2) has nothing to write back and is cheap.
__global__ __launch_bounds__(256) void k_score_fb(const float* __restrict__ cls,
                                                  const float* __restrict__ loc,
                                                  const float* __restrict__ anc,
                                                  unsigned* __restrict__ hist,
                                                  unsigned* __restrict__ meta, int n) {
    __shared__ unsigned lh[NBUCK];             // 64 KB
    __shared__ int slast;
    int tid = threadIdx.x, bid = blockIdx.x;
    for (int q = tid; q < NBUCK; q += 256) lh[q] = 0u;
    __syncthreads();
    for (int i = bid * 256 + tid; i < n; i += SBLK * 256) {
        unsigned u = make_key(cls, loc, anc, i);
        atomicAdd(&lh[u >> BSHIFT], 1u);
    }
    __syncthreads();
    for (int qq = 0; qq < NBUCK / 256; qq++) {
        int q = (qq + bid) & (NBUCK / 256 - 1);     // stagger across blocks
        int b = q * 256 + tid;
        unsigned v = lh[b];
        if (v) atomicAdd(&hist[b], v);
    }
    __syncthreads();
    if (tid == 0) {
        __threadfence();                        // cheap: atomic-only dirty set
        slast = (atomicAdd(&meta[2], 1u) == (unsigned)(SBLK - 1));
    }
    __syncthreads();
    if (!slast) return;
    __threadfence();                            // acquire
    unsigned* ps = lh;
    int base = tid * (NBUCK / 256);
    unsigned local = 0;
    for (int b = 0; b < NBUCK / 256; b++) local += hist[base + b];
    __syncthreads();
    ps[tid] = local;
    __syncthreads();
    for (int off = 1; off < 256; off <<= 1) {   // suffix-inclusive scan
        unsigned add = (tid + off < 256) ? ps[tid + off] : 0u;
        __syncthreads();
        ps[tid] += add;
        __syncthreads();
    }
    unsigned incl = ps[tid], excl = incl - local;
    if (incl >= (unsigned)PRE_NMS && excl < (unsigned)PRE_NMS) {
        unsigned cum = excl; int B = base;
        for (int b = NBUCK / 256 - 1; b >= 0; b--) {
            cum += hist[base + b];
            if (cum >= (unsigned)PRE_NMS) { B = base + b; break; }
        }
        meta[0] = (unsigned)B;
    }
}

// ============ K2: compact, recompute keys, wave-aggregated atomic =======
__global__ __launch_bounds__(256) void k_compactR(const float* __restrict__ cls,
                                                  const float* __restrict__ loc,
                                                  const float* __restrict__ anc,
                                                  unsigned* __restrict__ meta,
                                                  ull* __restrict__ cand, int n) {
    int i = blockIdx.x * blockDim.x + threadIdx.x;
    unsigned u = (i < n) ? make_key(cls, loc, anc, i) : 0u;
    unsigned B = meta[0];
    bool pred = (i < n) && ((u >> BSHIFT) >= B);
    ull mask = __ballot(pred);
    if (!mask) return;
    int lane = threadIdx.x & 63;
    int leader = __builtin_ctzll(mask);
    unsigned base = 0;
    if (lane == leader) base = atomicAdd(&meta[1], (unsigned)__popcll(mask));
    base = (unsigned)__shfl((int)base, leader, 64);
    if (pred) {
        unsigned p = base + (unsigned)__popcll(mask & ((1ull << lane) - 1ull));
        if (p < CAP) cand[p] = ((ull)(~u) << 32) | (unsigned)i;
    }
}

// ============ K3: exact rank; LAST block scatters + decodes ==============
__global__ __launch_bounds__(256) void k_rank_sc(const ull* __restrict__ cand,
                                                 unsigned* __restrict__ meta,
                                                 unsigned* __restrict__ rank,
                                                 const float* __restrict__ loc,
                                                 const float* __restrict__ anc,
                                                 float4* __restrict__ topbox,
                                                 ull* __restrict__ vmask) {
    __shared__ __align__(16) ull tile[RTILE];
    __shared__ int slast;
    int tid = threadIdx.x;
    int bx = blockIdx.x, by = blockIdx.y;
    unsigned C = meta[1]; if (C > CAP) C = CAP;
    int ibase = bx * 256 * RITEMS;
    ull ki[RITEMS]; unsigned cnt[RITEMS];
    #pragma unroll
    for (int r = 0; r < RITEMS; r++) {
        int i = ibase + r * 256 + tid;
        ki[r] = (i < (int)C) ? cand[i] : ~0ull;
        cnt[r] = 0u;
    }
    int j = by * RTILE + tid;
    tile[tid] = (j < (int)C) ? cand[j] : ~0ull;   // pad = +inf
    __syncthreads();
    const ulonglong2* t2 = (const ulonglong2*)tile;
    for (int q = 0; q < RTILE / 2; q++) {
        ulonglong2 v = t2[q];
        #pragma unroll
        for (int r = 0; r < RITEMS; r++)
            cnt[r] += (unsigned)(v.x < ki[r]) + (unsigned)(v.y < ki[r]);
    }
    #pragma unroll
    for (int r = 0; r < RITEMS; r++)
        if (cnt[r]) atomicAdd(&rank[ibase + r * 256 + tid], cnt[r]);
    __syncthreads();
    if (tid == 0) {
        __threadfence();                        // cheap: atomic-only dirty set
        slast = (atomicAdd(&meta[3], 1u) == gridDim.x * gridDim.y - 1);
    }
    __syncthreads();
    if (!slast) return;
    __threadfence();
    for (int i = tid; i < (int)C; i += 256) {
        ull kv = cand[i];
        unsigned uu = ~(unsigned)(kv >> 32);
        if (uu == 0u) continue;                // invalid box
        unsigned r = rank[i];
        if (r >= PRE_NMS) continue;            // outside top-6000
        int idx = (int)(unsigned)kv;
        topbox[r] = decode_box(loc, anc, idx);
        atomicOr(&vmask[r >> 6], 1ull << (r & 63));
    }
}

// ============ K4: suppression matrix (NO fences; boundary = visibility) ==
// One 64x64 upper-tri tile per wave; diag tiles also write transposed copy
// dgT for the scan's coalesced load. Lower-tri never written (garbage only
// pollutes already-consumed scan state words - validated R6/R7).
__global__ __launch_bounds__(256) void k_supp(const float4* __restrict__ topbox,
                                              ull* __restrict__ supp,
                                              ull* __restrict__ dgT) {
    __shared__ float4 cbox[256];
    int tid = threadIdx.x, bid = blockIdx.x;
    int wid = tid >> 6, lane = tid & 63;
    float4* cb4 = cbox + wid * 64;
    int vb = bid * 4 + wid;
    if (vb >= KW * KW) return;
    int rb = vb / KW, cb = vb - rb * KW;
    if (cb < rb) return;
    int jt = cb * 64 + lane;
    cb4[lane] = (jt < PRE_NMS) ? topbox[jt] : make_float4(3.f, 3.f, 3.f, 3.f);
    int i = rb * 64 + lane;
    if (i >= PRE_NMS) return;
    float4 bi = topbox[i];
    float ai = (bi.z - bi.x) * (bi.w - bi.y);
    ull bits = 0ull;
    int j0 = cb * 64;
    for (int jj = 0; jj < 64; jj++) {
        int j = j0 + jj;
        if (j <= i || j >= PRE_NMS) continue;
        float4 bj = cb4[jj];
        float aj = (bj.z - bj.x) * (bj.w - bj.y);
        float lx = fmaxf(bi.x, bj.x), ly = fmaxf(bi.y, bj.y);
        float rx = fminf(bi.z, bj.z), ry = fminf(bi.w, bj.w);
        float iw = fmaxf(rx - lx, 0.f), ih = fmaxf(ry - ly, 0.f);
        float inter = iw * ih;
        float iou = inter / (ai + aj - inter + 1e-12f);
        if (iou > IOU_TH) bits |= (1ull << jj);
    }
    supp[(size_t)i * KW + cb] = bits;
    if (cb == rb) dgT[cb * 64 + lane] = bits;   // transposed diag for scan
}

// ============ K5: chunked greedy scan (1 block) =========================
// Per 64-chunk: prefetch rows of first <=8 state-survivors (loads overlap
// the serial ALU resolve), resolve via LDS diag masks, merge kept rows.
__global__ __launch_bounds__(256) void k_scan(const ull* __restrict__ supp,
                                              const ull* __restrict__ dgT,
                                              const ull* __restrict__ vmask,
                                              const float4* __restrict__ topbox,
                                              float* __restrict__ out) {
    __shared__ __align__(16) ull dg[KW * 64];  // 47 KB
    __shared__ ull vml[KW];
    __shared__ int klist[POST_NMS];
    __shared__ int snk;
    int tid = threadIdx.x;
    int wid = tid >> 6, lane = tid & 63;
    for (int q = tid; q < KW * 64; q += 256) dg[q] = dgT[q];   // coalesced
    for (int q = tid; q < KW; q += 256) vml[q] = vmask[q];
    __syncthreads();
    if (wid == 0) {
        ull r0 = 0ull, r1 = 0ull;
        int nk = 0;
        bool done = false;
        for (int c = 0; c < KW && !done; c++) {
            ull dw = dg[c * 64 + lane];        // my row's diag word (LDS)
            ull st = (c < 64) ? bcast64(r0, c) : bcast64(r1, c - 64);
            ull todo = ~st & vml[c];
            // prefetch rows of first <=8 survivors (overlaps resolve)
            ull pf = todo;
            int pb[8]; ull pa[8], ph_[8];
            #pragma unroll
            for (int k = 0; k < 8; k++) {
                int b = pf ? __builtin_ctzll(pf) : -1;
                pb[k] = b;
                if (pf) pf &= pf - 1ull;
                const ull* p = supp + (size_t)(c * 64 + (b < 0 ? 0 : b)) * KW;
                pa[k]  = (b >= 0) ? p[lane] : 0ull;
                ph_[k] = (b >= 0 && lane < KW - 64) ? p[64 + lane] : 0ull;
            }
            // serial resolve: shfl/ALU only
            ull kept = 0ull;
            while (todo) {
                int b = __builtin_ctzll(todo);
                kept |= 1ull << b;
                if (lane == 0) klist[nk] = c * 64 + b;
                nk++;
                if (nk == POST_NMS) { done = true; break; }
                ull wb = bcast64(dw, b);
                todo &= ~wb;
                todo &= ~(1ull << b);
            }
            if (done) break;
            // merge prefetched kept rows
            #pragma unroll
            for (int k = 0; k < 8; k++) {
                if (pb[k] >= 0 && (kept & (1ull << pb[k]))) {
                    r0 |= pa[k]; r1 |= ph_[k];
                    kept &= ~(1ull << pb[k]);
                }
            }
            // rare leftovers (>8 keeps in one chunk): 4-wide batches
            while (kept) {
                int b0 = __builtin_ctzll(kept); kept &= kept - 1ull;
                int b1 = -1, b2 = -1, b3 = -1;
                if (kept) { b1 = __builtin_ctzll(kept); kept &= kept - 1ull; }
                if (kept) { b2 = __builtin_ctzll(kept); kept &= kept - 1ull; }
                if (kept) { b3 = __builtin_ctzll(kept); kept &= kept - 1ull; }
                const ull* p0 = supp + (size_t)(c * 64 + b0) * KW;
                ull a0 = p0[lane], h0 = (lane < KW - 64) ? p0[64 + lane] : 0ull;
                ull a1 = 0, h1 = 0, a2 = 0, h2 = 0, a3 = 0, h3 = 0;
                if (b1 >= 0) { const ull* p = supp + (size_t)(c * 64 + b1) * KW;
                               a1 = p[lane]; h1 = (lane < KW - 64) ? p[64 + lane] : 0ull; }
                if (b2 >= 0) { const ull* p = supp + (size_t)(c * 64 + b2) * KW;
                               a2 = p[lane]; h2 = (lane < KW - 64) ? p[64 + lane] : 0ull; }
                if (b3 >= 0) { const ull* p = supp + (size_t)(c * 64 + b3) * KW;
                               a3 = p[lane]; h3 = (lane < KW - 64) ? p[64 + lane] : 0ull; }
                r0 |= a0 | a1 | a2 | a3;
                r1 |= h0 | h1 | h2 | h3;
            }
        }
        if (lane == 0) snk = nk;
    }
    __syncthreads();
    int nk = snk;
    for (int q = tid; q < POST_NMS; q += 256)
        ((float4*)out)[q] = (q < nk) ? topbox[klist[q]]
                                     : make_float4(0.f, 0.f, 0.f, 0.f);
}

// =====================  small-ws fallback (R5-validated)  ================
__global__ __launch_bounds__(256) void k_score(const float* __restrict__ cls,
                                               const float* __restrict__ loc,
                                               const float* __restrict__ anc,
                                               unsigned* __restrict__ hist, int n) {
    __shared__ unsigned lh[NBUCK];
    int tid = threadIdx.x, bid = blockIdx.x;
    for (int q = tid; q < NBUCK; q += 256) lh[q] = 0u;
    __syncthreads();
    for (int i = bid * 256 + tid; i < n; i += SBLK * 256) {
        unsigned u = make_key(cls, loc, anc, i);
        atomicAdd(&lh[u >> BSHIFT], 1u);
    }
    __syncthreads();
    for (int qq = 0; qq < NBUCK / 256; qq++) {
        int q = (qq + bid) & (NBUCK / 256 - 1);
        int b = q * 256 + tid;
        unsigned v = lh[b];
        if (v) atomicAdd(&hist[b], v);
    }
}

__global__ __launch_bounds__(1024) void k_findb(const unsigned* __restrict__ hist,
                                                unsigned* __restrict__ meta) {
    __shared__ unsigned ps[1024];
    int t = threadIdx.x;
    int base = t * (NBUCK / 1024);
    unsigned local = 0;
    for (int b = 0; b < NBUCK / 1024; b++) local += hist[base + b];
    ps[t] = local;
    __syncthreads();
    for (int off = 1; off < 1024; off <<= 1) {
        unsigned add = (t + off < 1024) ? ps[t + off] : 0u;
        __syncthreads();
        ps[t] += add;
        __syncthreads();
    }
    unsigned incl = ps[t], excl = incl - local;
    if (incl >= (unsigned)PRE_NMS && excl < (unsigned)PRE_NMS) {
        unsigned cum = excl; int B = base;
        for (int b = NBUCK / 1024 - 1; b >= 0; b--) {
            cum += hist[base + b];
            if (cum >= (unsigned)PRE_NMS) { B = base + b; break; }
        }
        meta[0] = (unsigned)B;
    }
}

__global__ __launch_bounds__(256) void k_rank(const ull* __restrict__ cand,
                                              const unsigned* __restrict__ meta,
                                              unsigned* __restrict__ rank,
                                              float4* __restrict__ topbox) {
    __shared__ __align__(16) ull tile[RTILE];
    int tid = threadIdx.x;
    int bx = blockIdx.x, by = blockIdx.y;
    unsigned C = meta[1]; if (C > CAP) C = CAP;
    if (by == 0) {
        int per = TB_PAD / (CAP / (256 * RITEMS));
        int s0 = bx * per;
        for (int q = tid; q < per; q += 256)
            topbox[s0 + q] = make_float4(-1.f, -1.f, -1.f, -1.f);
    }
    int ibase = bx * 256 * RITEMS;
    ull ki[RITEMS]; unsigned cnt[RITEMS];
    #pragma unroll
    for (int r = 0; r < RITEMS; r++) {
        int i = ibase + r * 256 + tid;
        ki[r] = (i < (int)C) ? cand[i] : ~0ull;
        cnt[r] = 0u;
    }
    int j = by * RTILE + tid;
    tile[tid] = (j < (int)C) ? cand[j] : ~0ull;
    __syncthreads();
    const ulonglong2* t2 = (const ulonglong2*)tile;
    for (int q = 0; q < RTILE / 2; q++) {
        ulonglong2 v = t2[q];
        #pragma unroll
        for (int r = 0; r < RITEMS; r++)
            cnt[r] += (unsigned)(v.x < ki[r]) + (unsigned)(v.y < ki[r]);
    }
    #pragma unroll
    for (int r = 0; r < RITEMS; r++)
        if (cnt[r]) atomicAdd(&rank[ibase + r * 256 + tid], cnt[r]);
}

__global__ __launch_bounds__(256) void k_scatter(const ull* __restrict__ cand,
                                                 const unsigned* __restrict__ meta,
                                                 const unsigned* __restrict__ rank,
                                                 const float* __restrict__ loc,
                                                 const float* __restrict__ anc,
                                                 float4* __restrict__ topbox,
                                                 ull* __restrict__ vmask) {
    int i = blockIdx.x * 256 + threadIdx.x;
    unsigned C = meta[1]; if (C > CAP) C = CAP;
    if (i >= (int)C) return;
    ull kv = cand[i];
    unsigned uu = ~(unsigned)(kv >> 32);
    if (uu == 0u) return;
    unsigned r = rank[i];
    if (r >= PRE_NMS) return;
    int idx = (int)(unsigned)kv;
    topbox[r] = decode_box(loc, anc, idx);
    atomicOr(&vmask[r >> 6], 1ull << (r & 63));
}

__global__ __launch_bounds__(64) void k_nms(const float4* __restrict__ topbox,
                                            float* __restrict__ out) {
    int l = threadIdx.x;
    float4 kb[5];
    int nk = 0;
    for (int q0 = 0; q0 < TB_PAD && nk < POST_NMS; q0 += 64) {
        float4 myb = topbox[q0 + l];
        for (int b = 0; b < 64 && nk < POST_NMS; b++) {
            float4 bb;
            bb.x = __shfl(myb.x, b, 64);
            bb.y = __shfl(myb.y, b, 64);
            bb.z = __shfl(myb.z, b, 64);
            bb.w = __shfl(myb.w, b, 64);
            if (bb.x < 0.f) continue;
            float ab = (bb.z - bb.x) * (bb.w - bb.y);
            bool sup = false;
            #pragma unroll
            for (int r = 0; r < 5; r++) {
                int s = r * 64 + l;
                if (s < nk) {
                    float4 kv = kb[r];
                    float ak = (kv.z - kv.x) * (kv.w - kv.y);
                    float lx = fmaxf(bb.x, kv.x), ly = fmaxf(bb.y, kv.y);
                    float rx = fminf(bb.z, kv.z), ry = fminf(bb.w, kv.w);
                    float iw = fmaxf(rx - lx, 0.f), ih = fmaxf(ry - ly, 0.f);
                    float inter = iw * ih;
                    float iou = inter / (ab + ak - inter + 1e-12f);
                    sup |= (iou > IOU_TH);
                }
            }
            if (!__any(sup)) {
                if (l == (nk & 63)) kb[nk >> 6] = bb;
                if (l < 4) {
                    float v = (l == 0) ? bb.x : (l == 1) ? bb.y : (l == 2) ? bb.z : bb.w;
                    out[4 * nk + l] = v;
                }
                nk++;
            }
        }
    }
    for (int t = nk * 4 + l; t < POST_NMS * 4; t += 64) out[t] = 0.f;
}

extern "C" void kernel_launch(void* const* d_in, const int* in_sizes, int n_in,
                              void* d_out, int out_size, void* d_ws, size_t ws_size,
                              hipStream_t stream) {
    const int N = in_sizes[0] / 2;             // 202500
    const float* cls = (const float*)d_in[0];
    const float* loc = (const float*)d_in[1];
    const float* anc = (const float*)d_in[2];
    float* out = (float*)d_out;

    char* ws = (char*)d_ws;
    size_t off = 0;
    auto take = [&](size_t bytes) {
        size_t o = off;
        off += (bytes + 255) & ~(size_t)255;
        return o;
    };
    // zero region (one memset): hist + meta/vmask + rank
    unsigned* hist = (unsigned*)(ws + take((size_t)NBUCK * 4));      // 64 KB
    char*     mblk = ws + take(1024);
    unsigned* meta  = (unsigned*)mblk;         // [0]=B [1]=C [2..3]=tickets
    ull*      vmask = (ull*)(mblk + 256);      // 94 words
    unsigned* rank = (unsigned*)(ws + take((size_t)CAP * 4));        // 32 KB
    size_t zlen = off;
    ull*    cand   = (ull*)(ws + take((size_t)CAP * 8));             // 64 KB
    float4* topbox = (float4*)(ws + take((size_t)TB_PAD * 16));      // 94 KB
    ull*    dgT    = (ull*)(ws + take((size_t)KW * 64 * 8));         // 47 KB
    ull*    supp   = (ull*)(ws + take((size_t)PRE_NMS * KW * 8));    // 4.42 MB
    size_t full_need = off;
    const bool fast = (ws_size >= full_need);   // constant across calls

    hipMemsetAsync(ws, 0, zlen, stream);

    if (fast) {
        k_score_fb<<<SBLK, 256, 0, stream>>>(cls, loc, anc, hist, meta, N);
        k_compactR<<<(N + 255) / 256, 256, 0, stream>>>(cls, loc, anc, meta, cand, N);
        k_rank_sc<<<dim3(CAP / (256 * RITEMS), CAP / RTILE), 256, 0, stream>>>(
            cand, meta, rank, loc, anc, topbox, vmask);
        k_supp<<<(KW * KW + 3) / 4, 256, 0, stream>>>(topbox, supp, dgT);
        k_scan<<<1, 256, 0, stream>>>(supp, dgT, vmask, topbox, out);
    } else {
        k_score<<<SBLK, 256, 0, stream>>>(cls, loc, anc, hist, N);
        k_findb<<<1, 1024, 0, stream>>>(hist, meta);
        k_compactR<<<(N + 255) / 256, 256, 0, stream>>>(cls, loc, anc, meta, cand, N);
        k_rank<<<dim3(CAP / (256 * RITEMS), CAP / RTILE), 256, 0, stream>>>(cand, meta, rank, topbox);
        k_scatter<<<CAP / 256, 256, 0, stream>>>(cand, meta, rank, loc, anc, topbox, vmask);
        k_nms<<<1, 64, 0, stream>>>(topbox, out);
    }
}

// Round 9
// 271.978 us; speedup vs baseline: 1.2832x; 1.0202x over previous
//
#include <hip/hip_runtime.h>
#include <hip/hip_bf16.h>

#define NANCH 202500
#define PRE_NMS 6000
#define POST_NMS 300
#define KW 94            // ceil(6016/64) words per supp row
#define NCH 47           // 128-wide chunks
#define CAP 8192
#define NBUCK 16384
#define BSHIFT 18
#define IOU_TH 0.7f
#define MIN_SIZE 0.016f
#define TB_PAD 6016
#define RITEMS 8
#define RTILE 256
#define SBLK 256         // k1 grid blocks

typedef unsigned long long ull;

// ---------------- shared decode / key helpers ---------------------------
__device__ inline float4 decode_box(const float* __restrict__ loc,
                                    const float* __restrict__ anc, int i) {
    float4 a = ((const float4*)anc)[i];
    float4 t = ((const float4*)loc)[i];
    float pw = a.z - a.x, ph = a.w - a.y;
    float pcx = (a.x + a.z) * 0.5f, pcy = (a.y + a.w) * 0.5f;
    float cx = t.x * pw + pcx, cy = t.y * ph + pcy;
    float w = expf(t.z) * pw, h = expf(t.w) * ph;
    float x1 = fminf(fmaxf(cx - 0.5f * w, 0.f), 1.f);
    float y1 = fminf(fmaxf(cy - 0.5f * h, 0.f), 1.f);
    float x2 = fminf(fmaxf(cx + 0.5f * w, 0.f), 1.f);
    float y2 = fminf(fmaxf(cy + 0.5f * h, 0.f), 1.f);
    return make_float4(x1, y1, x2, y2);
}

__device__ inline unsigned make_key(const float* __restrict__ cls,
                                    const float* __restrict__ loc,
                                    const float* __restrict__ anc, int i) {
    float2 c = ((const float2*)cls)[i];
    float d = c.y - c.x;                       // monotone proxy for softmax[:,1]
    float4 b = decode_box(loc, anc, i);
    bool valid = ((b.z - b.x) >= MIN_SIZE) && ((b.w - b.y) >= MIN_SIZE);
    unsigned ib = __float_as_uint(d);
    unsigned u = (ib & 0x80000000u) ? ~ib : (ib | 0x80000000u);  // monotonic key
    return valid ? u : 0u;
}

__device__ inline ull bcast64(ull v, int lane) {
    unsigned lo = (unsigned)v, hi = (unsigned)(v >> 32);
    lo = (unsigned)__shfl((int)lo, lane, 64);
    hi = (unsigned)__shfl((int)hi, lane, 64);
    return ((ull)hi << 32) | lo;
}

// ============ K1: LDS histogram; LAST block finds boundary ==============
__global__ __launch_bounds__(256) void k_score_fb(const float* __restrict__ cls,
                                                  const float* __restrict__ loc,
                                                  const float* __restrict__ anc,
                                                  unsigned* __restrict__ hist,
                                                  unsigned* __restrict__ meta, int n) {
    __shared__ unsigned lh[NBUCK];             // 64 KB
    __shared__ int slast;
    int tid = threadIdx.x, bid = blockIdx.x;
    for (int q = tid; q < NBUCK; q += 256) lh[q] = 0u;
    __syncthreads();
    for (int i = bid * 256 + tid; i < n; i += SBLK * 256) {
        unsigned u = make_key(cls, loc, anc, i);
        atomicAdd(&lh[u >> BSHIFT], 1u);
    }
    __syncthreads();
    for (int qq = 0; qq < NBUCK / 256; qq++) {
        int q = (qq + bid) & (NBUCK / 256 - 1);     // stagger across blocks
        int b = q * 256 + tid;
        unsigned v = lh[b];
        if (v) atomicAdd(&hist[b], v);
    }
    __syncthreads();
    if (tid == 0) {
        __threadfence();                        // cheap: atomic-only dirty set
        slast = (atomicAdd(&meta[2], 1u) == (unsigned)(SBLK - 1));
    }
    __syncthreads();
    if (!slast) return;
    __threadfence();                            // acquire
    unsigned* ps = lh;
    int base = tid * (NBUCK / 256);
    unsigned local = 0;
    for (int b = 0; b < NBUCK / 256; b++) local += hist[base + b];
    __syncthreads();
    ps[tid] = local;
    __syncthreads();
    for (int off = 1; off < 256; off <<= 1) {   // suffix-inclusive scan
        unsigned add = (tid + off < 256) ? ps[tid + off] : 0u;
        __syncthreads();
        ps[tid] += add;
        __syncthreads();
    }
    unsigned incl = ps[tid], excl = incl - local;
    if (incl >= (unsigned)PRE_NMS && excl < (unsigned)PRE_NMS) {
        unsigned cum = excl; int B = base;
        for (int b = NBUCK / 256 - 1; b >= 0; b--) {
            cum += hist[base + b];
            if (cum >= (unsigned)PRE_NMS) { B = base + b; break; }
        }
        meta[0] = (unsigned)B;
    }
}

// ============ K2: compact, recompute keys, wave-aggregated atomic =======
__global__ __launch_bounds__(256) void k_compactR(const float* __restrict__ cls,
                                                  const float* __restrict__ loc,
                                                  const float* __restrict__ anc,
                                                  unsigned* __restrict__ meta,
                                                  ull* __restrict__ cand, int n) {
    int i = blockIdx.x * blockDim.x + threadIdx.x;
    unsigned u = (i < n) ? make_key(cls, loc, anc, i) : 0u;
    unsigned B = meta[0];
    bool pred = (i < n) && ((u >> BSHIFT) >= B);
    ull mask = __ballot(pred);
    if (!mask) return;
    int lane = threadIdx.x & 63;
    int leader = __builtin_ctzll(mask);
    unsigned base = 0;
    if (lane == leader) base = atomicAdd(&meta[1], (unsigned)__popcll(mask));
    base = (unsigned)__shfl((int)base, leader, 64);
    if (pred) {
        unsigned p = base + (unsigned)__popcll(mask & ((1ull << lane) - 1ull));
        if (p < CAP) cand[p] = ((ull)(~u) << 32) | (unsigned)i;
    }
}

// ============ K3: exact rank; LAST block scatters + decodes ==============
__global__ __launch_bounds__(256) void k_rank_sc(const ull* __restrict__ cand,
                                                 unsigned* __restrict__ meta,
                                                 unsigned* __restrict__ rank,
                                                 const float* __restrict__ loc,
                                                 const float* __restrict__ anc,
                                                 float4* __restrict__ topbox,
                                                 ull* __restrict__ vmask) {
    __shared__ __align__(16) ull tile[RTILE];
    __shared__ int slast;
    int tid = threadIdx.x;
    int bx = blockIdx.x, by = blockIdx.y;
    unsigned C = meta[1]; if (C > CAP) C = CAP;
    int ibase = bx * 256 * RITEMS;
    ull ki[RITEMS]; unsigned cnt[RITEMS];
    #pragma unroll
    for (int r = 0; r < RITEMS; r++) {
        int i = ibase + r * 256 + tid;
        ki[r] = (i < (int)C) ? cand[i] : ~0ull;
        cnt[r] = 0u;
    }
    int j = by * RTILE + tid;
    tile[tid] = (j < (int)C) ? cand[j] : ~0ull;   // pad = +inf
    __syncthreads();
    const ulonglong2* t2 = (const ulonglong2*)tile;
    for (int q = 0; q < RTILE / 2; q++) {
        ulonglong2 v = t2[q];
        #pragma unroll
        for (int r = 0; r < RITEMS; r++)
            cnt[r] += (unsigned)(v.x < ki[r]) + (unsigned)(v.y < ki[r]);
    }
    #pragma unroll
    for (int r = 0; r < RITEMS; r++)
        if (cnt[r]) atomicAdd(&rank[ibase + r * 256 + tid], cnt[r]);
    __syncthreads();
    if (tid == 0) {
        __threadfence();                        // cheap: atomic-only dirty set
        slast = (atomicAdd(&meta[3], 1u) == gridDim.x * gridDim.y - 1);
    }
    __syncthreads();
    if (!slast) return;
    __threadfence();
    for (int i = tid; i < (int)C; i += 256) {
        ull kv = cand[i];
        unsigned uu = ~(unsigned)(kv >> 32);
        if (uu == 0u) continue;                // invalid box
        unsigned r = rank[i];
        if (r >= PRE_NMS) continue;            // outside top-6000
        int idx = (int)(unsigned)kv;
        topbox[r] = decode_box(loc, anc, idx);
        atomicOr(&vmask[r >> 6], 1ull << (r & 63));
    }
}

// ============ K4: suppression matrix + 128-chunk diag array ==============
// One 64x64 upper-tri tile per wave. Block-diagonal info additionally goes
// to dg2[q][p][w]: suppression of chunk-q local position p over local words
// w=0 ([0,64)) / w=1 ([64,128)). Only upper-tri entries are written; the
// never-written ones ([p>=64][0], rows >= PRE_NMS) are provably never
// consumed by the scan.
__global__ __launch_bounds__(256) void k_supp(const float4* __restrict__ topbox,
                                              ull* __restrict__ supp,
                                              ull* __restrict__ dg2) {
    __shared__ float4 cbox[256];
    int tid = threadIdx.x, bid = blockIdx.x;
    int wid = tid >> 6, lane = tid & 63;
    float4* cb4 = cbox + wid * 64;
    int vb = bid * 4 + wid;
    if (vb >= KW * KW) return;
    int rb = vb / KW, cb = vb - rb * KW;
    if (cb < rb) return;
    int jt = cb * 64 + lane;
    cb4[lane] = (jt < PRE_NMS) ? topbox[jt] : make_float4(3.f, 3.f, 3.f, 3.f);
    int i = rb * 64 + lane;
    if (i >= PRE_NMS) return;
    float4 bi = topbox[i];
    float ai = (bi.z - bi.x) * (bi.w - bi.y);
    ull bits = 0ull;
    int j0 = cb * 64;
    for (int jj = 0; jj < 64; jj++) {
        int j = j0 + jj;
        if (j <= i || j >= PRE_NMS) continue;
        float4 bj = cb4[jj];
        float aj = (bj.z - bj.x) * (bj.w - bj.y);
        float lx = fmaxf(bi.x, bj.x), ly = fmaxf(bi.y, bj.y);
        float rx = fminf(bi.z, bj.z), ry = fminf(bi.w, bj.w);
        float iw = fmaxf(rx - lx, 0.f), ih = fmaxf(ry - ly, 0.f);
        float inter = iw * ih;
        float iou = inter / (ai + aj - inter + 1e-12f);
        if (iou > IOU_TH) bits |= (1ull << jj);
    }
    supp[(size_t)i * KW + cb] = bits;
    if (cb == rb) {
        int q = rb >> 1;
        if (rb & 1) dg2[q * 256 + (64 + lane) * 2 + 1] = bits;
        else        dg2[q * 256 + lane * 2 + 0]        = bits;
    } else if (((rb & 1) == 0) && cb == rb + 1) {
        dg2[(rb >> 1) * 256 + lane * 2 + 1] = bits;
    }
}

// ============ K5: 128-chunk greedy scan (1 block, wave 0 serial) ========
// Per chunk: resolve both 64-halves with pure shfl/ALU (every surviving
// todo bit is a keep), then ONE batched row-merge round trip. Diag words
// for chunk q+1 are prefetched before the merge loads (software pipeline).
__global__ __launch_bounds__(256) void k_scan(const ull* __restrict__ supp,
                                              const ull* __restrict__ dg2,
                                              const ull* __restrict__ vmask,
                                              const float4* __restrict__ topbox,
                                              float* __restrict__ out) {
    __shared__ ull vml[KW];
    __shared__ int klist[POST_NMS];
    __shared__ int snk;
    int tid = threadIdx.x;
    int wid = tid >> 6, lane = tid & 63;
    for (int q = tid; q < KW; q += 256) vml[q] = vmask[q];
    __syncthreads();
    if (wid == 0) {
        ull r0 = 0ull, r1 = 0ull;
        int nk = 0;
        bool done = false;
        ull aw0 = dg2[lane * 2 + 0];            // chunk 0 diag words
        ull aw1 = dg2[lane * 2 + 1];
        ull bw1 = dg2[128 + lane * 2 + 1];
        for (int q = 0; q < NCH && !done; q++) {
            // prefetch next chunk's diag words (overlaps this chunk's merge)
            ull naw0 = 0, naw1 = 0, nbw1 = 0;
            if (q + 1 < NCH) {
                const ull* pg = dg2 + (q + 1) * 256;
                naw0 = pg[lane * 2 + 0];
                naw1 = pg[lane * 2 + 1];
                nbw1 = pg[128 + lane * 2 + 1];
            }
            int c0 = 2 * q, c1 = 2 * q + 1;
            ull st0 = (c0 < 64) ? bcast64(r0, c0) : bcast64(r1, c0 - 64);
            ull st1 = (c1 < 64) ? bcast64(r0, c1) : bcast64(r1, c1 - 64);
            ull todo0 = ~st0 & vml[c0];
            ull todo1 = ~st1 & vml[c1];
            ull kept0 = 0ull, kept1 = 0ull;
            while (todo0) {                     // first half: every bit = keep
                int b = __builtin_ctzll(todo0);
                kept0 |= 1ull << b;
                if (lane == 0) klist[nk] = q * 128 + b;
                nk++;
                if (nk == POST_NMS) { done = true; break; }
                ull w0 = bcast64(aw0, b);
                ull w1 = bcast64(aw1, b);
                todo0 &= ~w0; todo0 &= ~(1ull << b);
                todo1 &= ~w1;
            }
            if (!done) while (todo1) {          // second half
                int b = __builtin_ctzll(todo1);
                kept1 |= 1ull << b;
                if (lane == 0) klist[nk] = q * 128 + 64 + b;
                nk++;
                if (nk == POST_NMS) { done = true; break; }
                ull w1 = bcast64(bw1, b);
                todo1 &= ~w1; todo1 &= ~(1ull << b);
            }
            if (done) break;
            // merge kept rows into global state, 4-wide batches
            while (kept0 | kept1) {
                int g0 = -1, g1 = -1, g2 = -1, g3 = -1;
                if (kept0) { int b = __builtin_ctzll(kept0); kept0 &= kept0 - 1ull; g0 = q * 128 + b; }
                else if (kept1) { int b = __builtin_ctzll(kept1); kept1 &= kept1 - 1ull; g0 = q * 128 + 64 + b; }
                if (kept0) { int b = __builtin_ctzll(kept0); kept0 &= kept0 - 1ull; g1 = q * 128 + b; }
                else if (kept1) { int b = __builtin_ctzll(kept1); kept1 &= kept1 - 1ull; g1 = q * 128 + 64 + b; }
                if (kept0) { int b = __builtin_ctzll(kept0); kept0 &= kept0 - 1ull; g2 = q * 128 + b; }
                else if (kept1) { int b = __builtin_ctzll(kept1); kept1 &= kept1 - 1ull; g2 = q * 128 + 64 + b; }
                if (kept0) { int b = __builtin_ctzll(kept0); kept0 &= kept0 - 1ull; g3 = q * 128 + b; }
                else if (kept1) { int b = __builtin_ctzll(kept1); kept1 &= kept1 - 1ull; g3 = q * 128 + 64 + b; }
                ull a0 = 0, h0 = 0, a1 = 0, h1 = 0, a2 = 0, h2 = 0, a3 = 0, h3 = 0;
                { const ull* p = supp + (size_t)g0 * KW;
                  a0 = p[lane]; h0 = (lane < KW - 64) ? p[64 + lane] : 0ull; }
                if (g1 >= 0) { const ull* p = supp + (size_t)g1 * KW;
                               a1 = p[lane]; h1 = (lane < KW - 64) ? p[64 + lane] : 0ull; }
                if (g2 >= 0) { const ull* p = supp + (size_t)g2 * KW;
                               a2 = p[lane]; h2 = (lane < KW - 64) ? p[64 + lane] : 0ull; }
                if (g3 >= 0) { const ull* p = supp + (size_t)g3 * KW;
                               a3 = p[lane]; h3 = (lane < KW - 64) ? p[64 + lane] : 0ull; }
                r0 |= a0 | a1 | a2 | a3;
                r1 |= h0 | h1 | h2 | h3;
            }
            aw0 = naw0; aw1 = naw1; bw1 = nbw1;
        }
        if (lane == 0) snk = nk;
    }
    __syncthreads();
    int nk = snk;
    for (int q = tid; q < POST_NMS; q += 256)
        ((float4*)out)[q] = (q < nk) ? topbox[klist[q]]
                                     : make_float4(0.f, 0.f, 0.f, 0.f);
}

// =====================  small-ws fallback (R5-validated)  ================
__global__ __launch_bounds__(256) void k_score(const float* __restrict__ cls,
                                               const float* __restrict__ loc,
                                               const float* __restrict__ anc,
                                               unsigned* __restrict__ hist, int n) {
    __shared__ unsigned lh[NBUCK];
    int tid = threadIdx.x, bid = blockIdx.x;
    for (int q = tid; q < NBUCK; q += 256) lh[q] = 0u;
    __syncthreads();
    for (int i = bid * 256 + tid; i < n; i += SBLK * 256) {
        unsigned u = make_key(cls, loc, anc, i);
        atomicAdd(&lh[u >> BSHIFT], 1u);
    }
    __syncthreads();
    for (int qq = 0; qq < NBUCK / 256; qq++) {
        int q = (qq + bid) & (NBUCK / 256 - 1);
        int b = q * 256 + tid;
        unsigned v = lh[b];
        if (v) atomicAdd(&hist[b], v);
    }
}

__global__ __launch_bounds__(1024) void k_findb(const unsigned* __restrict__ hist,
                                                unsigned* __restrict__ meta) {
    __shared__ unsigned ps[1024];
    int t = threadIdx.x;
    int base = t * (NBUCK / 1024);
    unsigned local = 0;
    for (int b = 0; b < NBUCK / 1024; b++) local += hist[base + b];
    ps[t] = local;
    __syncthreads();
    for (int off = 1; off < 1024; off <<= 1) {
        unsigned add = (t + off < 1024) ? ps[t + off] : 0u;
        __syncthreads();
        ps[t] += add;
        __syncthreads();
    }
    unsigned incl = ps[t], excl = incl - local;
    if (incl >= (unsigned)PRE_NMS && excl < (unsigned)PRE_NMS) {
        unsigned cum = excl; int B = base;
        for (int b = NBUCK / 1024 - 1; b >= 0; b--) {
            cum += hist[base + b];
            if (cum >= (unsigned)PRE_NMS) { B = base + b; break; }
        }
        meta[0] = (unsigned)B;
    }
}

__global__ __launch_bounds__(256) void k_rank(const ull* __restrict__ cand,
                                              const unsigned* __restrict__ meta,
                                              unsigned* __restrict__ rank,
                                              float4* __restrict__ topbox) {
    __shared__ __align__(16) ull tile[RTILE];
    int tid = threadIdx.x;
    int bx = blockIdx.x, by = blockIdx.y;
    unsigned C = meta[1]; if (C > CAP) C = CAP;
    if (by == 0) {
        int per = TB_PAD / (CAP / (256 * RITEMS));
        int s0 = bx * per;
        for (int q = tid; q < per; q += 256)
            topbox[s0 + q] = make_float4(-1.f, -1.f, -1.f, -1.f);
    }
    int ibase = bx * 256 * RITEMS;
    ull ki[RITEMS]; unsigned cnt[RITEMS];
    #pragma unroll
    for (int r = 0; r < RITEMS; r++) {
        int i = ibase + r * 256 + tid;
        ki[r] = (i < (int)C) ? cand[i] : ~0ull;
        cnt[r] = 0u;
    }
    int j = by * RTILE + tid;
    tile[tid] = (j < (int)C) ? cand[j] : ~0ull;
    __syncthreads();
    const ulonglong2* t2 = (const ulonglong2*)tile;
    for (int q = 0; q < RTILE / 2; q++) {
        ulonglong2 v = t2[q];
        #pragma unroll
        for (int r = 0; r < RITEMS; r++)
            cnt[r] += (unsigned)(v.x < ki[r]) + (unsigned)(v.y < ki[r]);
    }
    #pragma unroll
    for (int r = 0; r < RITEMS; r++)
        if (cnt[r]) atomicAdd(&rank[ibase + r * 256 + tid], cnt[r]);
}

__global__ __launch_bounds__(256) void k_scatter(const ull* __restrict__ cand,
                                                 const unsigned* __restrict__ meta,
                                                 const unsigned* __restrict__ rank,
                                                 const float* __restrict__ loc,
                                                 const float* __restrict__ anc,
                                                 float4* __restrict__ topbox,
                                                 ull* __restrict__ vmask) {
    int i = blockIdx.x * 256 + threadIdx.x;
    unsigned C = meta[1]; if (C > CAP) C = CAP;
    if (i >= (int)C) return;
    ull kv = cand[i];
    unsigned uu = ~(unsigned)(kv >> 32);
    if (uu == 0u) return;
    unsigned r = rank[i];
    if (r >= PRE_NMS) return;
    int idx = (int)(unsigned)kv;
    topbox[r] = decode_box(loc, anc, idx);
    atomicOr(&vmask[r >> 6], 1ull << (r & 63));
}

__global__ __launch_bounds__(64) void k_nms(const float4* __restrict__ topbox,
                                            float* __restrict__ out) {
    int l = threadIdx.x;
    float4 kb[5];
    int nk = 0;
    for (int q0 = 0; q0 < TB_PAD && nk < POST_NMS; q0 += 64) {
        float4 myb = topbox[q0 + l];
        for (int b = 0; b < 64 && nk < POST_NMS; b++) {
            float4 bb;
            bb.x = __shfl(myb.x, b, 64);
            bb.y = __shfl(myb.y, b, 64);
            bb.z = __shfl(myb.z, b, 64);
            bb.w = __shfl(myb.w, b, 64);
            if (bb.x < 0.f) continue;
            float ab = (bb.z - bb.x) * (bb.w - bb.y);
            bool sup = false;
            #pragma unroll
            for (int r = 0; r < 5; r++) {
                int s = r * 64 + l;
                if (s < nk) {
                    float4 kv = kb[r];
                    float ak = (kv.z - kv.x) * (kv.w - kv.y);
                    float lx = fmaxf(bb.x, kv.x), ly = fmaxf(bb.y, kv.y);
                    float rx = fminf(bb.z, kv.z), ry = fminf(bb.w, kv.w);
                    float iw = fmaxf(rx - lx, 0.f), ih = fmaxf(ry - ly, 0.f);
                    float inter = iw * ih;
                    float iou = inter / (ab + ak - inter + 1e-12f);
                    sup |= (iou > IOU_TH);
                }
            }
            if (!__any(sup)) {
                if (l == (nk & 63)) kb[nk >> 6] = bb;
                if (l < 4) {
                    float v = (l == 0) ? bb.x : (l == 1) ? bb.y : (l == 2) ? bb.z : bb.w;
                    out[4 * nk + l] = v;
                }
                nk++;
            }
        }
    }
    for (int t = nk * 4 + l; t < POST_NMS * 4; t += 64) out[t] = 0.f;
}

extern "C" void kernel_launch(void* const* d_in, const int* in_sizes, int n_in,
                              void* d_out, int out_size, void* d_ws, size_t ws_size,
                              hipStream_t stream) {
    const int N = in_sizes[0] / 2;             // 202500
    const float* cls = (const float*)d_in[0];
    const float* loc = (const float*)d_in[1];
    const float* anc = (const float*)d_in[2];
    float* out = (float*)d_out;

    char* ws = (char*)d_ws;
    size_t off = 0;
    auto take = [&](size_t bytes) {
        size_t o = off;
        off += (bytes + 255) & ~(size_t)255;
        return o;
    };
    // zero region (one memset): hist + meta/vmask + rank
    unsigned* hist = (unsigned*)(ws + take((size_t)NBUCK * 4));      // 64 KB
    char*     mblk = ws + take(1024);
    unsigned* meta  = (unsigned*)mblk;         // [0]=B [1]=C [2..3]=tickets
    ull*      vmask = (ull*)(mblk + 256);      // 94 words
    unsigned* rank = (unsigned*)(ws + take((size_t)CAP * 4));        // 32 KB
    size_t zlen = off;
    ull*    cand   = (ull*)(ws + take((size_t)CAP * 8));             // 64 KB
    float4* topbox = (float4*)(ws + take((size_t)TB_PAD * 16));      // 94 KB
    ull*    dg2    = (ull*)(ws + take((size_t)NCH * 256 * 8));       // 94 KB
    ull*    supp   = (ull*)(ws + take((size_t)PRE_NMS * KW * 8));    // 4.42 MB
    size_t full_need = off;
    const bool fast = (ws_size >= full_need);   // constant across calls

    hipMemsetAsync(ws, 0, zlen, stream);

    if (fast) {
        k_score_fb<<<SBLK, 256, 0, stream>>>(cls, loc, anc, hist, meta, N);
        k_compactR<<<(N + 255) / 256, 256, 0, stream>>>(cls, loc, anc, meta, cand, N);
        k_rank_sc<<<dim3(CAP / (256 * RITEMS), CAP / RTILE), 256, 0, stream>>>(
            cand, meta, rank, loc, anc, topbox, vmask);
        k_supp<<<(KW * KW + 3) / 4, 256, 0, stream>>>(topbox, supp, dg2);
        k_scan<<<1, 256, 0, stream>>>(supp, dg2, vmask, topbox, out);
    } else {
        k_score<<<SBLK, 256, 0, stream>>>(cls, loc, anc, hist, N);
        k_findb<<<1, 1024, 0, stream>>>(hist, meta);
        k_compactR<<<(N + 255) / 256, 256, 0, stream>>>(cls, loc, anc, meta, cand, N);
        k_rank<<<dim3(CAP / (256 * RITEMS), CAP / RTILE), 256, 0, stream>>>(cand, meta, rank, topbox);
        k_scatter<<<CAP / 256, 256, 0, stream>>>(cand, meta, rank, loc, anc, topbox, vmask);
        k_nms<<<1, 64, 0, stream>>>(topbox, out);
    }
}

// Round 10
// 246.017 us; speedup vs baseline: 1.4186x; 1.1055x over previous
//
#include <hip/hip_runtime.h>
#include <hip/hip_bf16.h>

#define NANCH 202500
#define PRE_NMS 6000
#define POST_NMS 300
#define KW 94            // ceil(6016/64) words per supp row
#define NSC 12           // 512-row super-chunks (6144 >= 6016)
#define CAP 8192
#define NBUCK 16384
#define BSHIFT 18
#define IOU_TH 0.7f
#define MIN_SIZE 0.016f
#define TB_PAD 6016
#define RITEMS 8
#define RTILE 256
#define SBLK 256         // k1 grid blocks

typedef unsigned long long ull;

// ---------------- shared decode / key helpers ---------------------------
__device__ inline float4 decode_box(const float* __restrict__ loc,
                                    const float* __restrict__ anc, int i) {
    float4 a = ((const float4*)anc)[i];
    float4 t = ((const float4*)loc)[i];
    float pw = a.z - a.x, ph = a.w - a.y;
    float pcx = (a.x + a.z) * 0.5f, pcy = (a.y + a.w) * 0.5f;
    float cx = t.x * pw + pcx, cy = t.y * ph + pcy;
    float w = expf(t.z) * pw, h = expf(t.w) * ph;
    float x1 = fminf(fmaxf(cx - 0.5f * w, 0.f), 1.f);
    float y1 = fminf(fmaxf(cy - 0.5f * h, 0.f), 1.f);
    float x2 = fminf(fmaxf(cx + 0.5f * w, 0.f), 1.f);
    float y2 = fminf(fmaxf(cy + 0.5f * h, 0.f), 1.f);
    return make_float4(x1, y1, x2, y2);
}

__device__ inline unsigned make_key(const float* __restrict__ cls,
                                    const float* __restrict__ loc,
                                    const float* __restrict__ anc, int i) {
    float2 c = ((const float2*)cls)[i];
    float d = c.y - c.x;                       // monotone proxy for softmax[:,1]
    float4 b = decode_box(loc, anc, i);
    bool valid = ((b.z - b.x) >= MIN_SIZE) && ((b.w - b.y) >= MIN_SIZE);
    unsigned ib = __float_as_uint(d);
    unsigned u = (ib & 0x80000000u) ? ~ib : (ib | 0x80000000u);  // monotonic key
    return valid ? u : 0u;
}

__device__ inline ull bcast64(ull v, int lane) {
    unsigned lo = (unsigned)v, hi = (unsigned)(v >> 32);
    lo = (unsigned)__shfl((int)lo, lane, 64);
    hi = (unsigned)__shfl((int)hi, lane, 64);
    return ((ull)hi << 32) | lo;
}

// ============ K1: LDS histogram; LAST block finds boundary ==============
__global__ __launch_bounds__(256) void k_score_fb(const float* __restrict__ cls,
                                                  const float* __restrict__ loc,
                                                  const float* __restrict__ anc,
                                                  unsigned* __restrict__ hist,
                                                  unsigned* __restrict__ meta, int n) {
    __shared__ unsigned lh[NBUCK];             // 64 KB
    __shared__ int slast;
    int tid = threadIdx.x, bid = blockIdx.x;
    for (int q = tid; q < NBUCK; q += 256) lh[q] = 0u;
    __syncthreads();
    for (int i = bid * 256 + tid; i < n; i += SBLK * 256) {
        unsigned u = make_key(cls, loc, anc, i);
        atomicAdd(&lh[u >> BSHIFT], 1u);
    }
    __syncthreads();
    for (int qq = 0; qq < NBUCK / 256; qq++) {
        int q = (qq + bid) & (NBUCK / 256 - 1);     // stagger across blocks
        int b = q * 256 + tid;
        unsigned v = lh[b];
        if (v) atomicAdd(&hist[b], v);
    }
    __syncthreads();
    if (tid == 0) {
        __threadfence();                        // cheap: atomic-only dirty set
        slast = (atomicAdd(&meta[2], 1u) == (unsigned)(SBLK - 1));
    }
    __syncthreads();
    if (!slast) return;
    __threadfence();                            // acquire
    unsigned* ps = lh;
    int base = tid * (NBUCK / 256);
    unsigned local = 0;
    for (int b = 0; b < NBUCK / 256; b++) local += hist[base + b];
    __syncthreads();
    ps[tid] = local;
    __syncthreads();
    for (int off = 1; off < 256; off <<= 1) {   // suffix-inclusive scan
        unsigned add = (tid + off < 256) ? ps[tid + off] : 0u;
        __syncthreads();
        ps[tid] += add;
        __syncthreads();
    }
    unsigned incl = ps[tid], excl = incl - local;
    if (incl >= (unsigned)PRE_NMS && excl < (unsigned)PRE_NMS) {
        unsigned cum = excl; int B = base;
        for (int b = NBUCK / 256 - 1; b >= 0; b--) {
            cum += hist[base + b];
            if (cum >= (unsigned)PRE_NMS) { B = base + b; break; }
        }
        meta[0] = (unsigned)B;
    }
}

// ============ K2: compact, recompute keys, wave-aggregated atomic =======
__global__ __launch_bounds__(256) void k_compactR(const float* __restrict__ cls,
                                                  const float* __restrict__ loc,
                                                  const float* __restrict__ anc,
                                                  unsigned* __restrict__ meta,
                                                  ull* __restrict__ cand, int n) {
    int i = blockIdx.x * blockDim.x + threadIdx.x;
    unsigned u = (i < n) ? make_key(cls, loc, anc, i) : 0u;
    unsigned B = meta[0];
    bool pred = (i < n) && ((u >> BSHIFT) >= B);
    ull mask = __ballot(pred);
    if (!mask) return;
    int lane = threadIdx.x & 63;
    int leader = __builtin_ctzll(mask);
    unsigned base = 0;
    if (lane == leader) base = atomicAdd(&meta[1], (unsigned)__popcll(mask));
    base = (unsigned)__shfl((int)base, leader, 64);
    if (pred) {
        unsigned p = base + (unsigned)__popcll(mask & ((1ull << lane) - 1ull));
        if (p < CAP) cand[p] = ((ull)(~u) << 32) | (unsigned)i;
    }
}

// ============ K3: exact rank; LAST block scatters + decodes ==============
__global__ __launch_bounds__(256) void k_rank_sc(const ull* __restrict__ cand,
                                                 unsigned* __restrict__ meta,
                                                 unsigned* __restrict__ rank,
                                                 const float* __restrict__ loc,
                                                 const float* __restrict__ anc,
                                                 float4* __restrict__ topbox,
                                                 ull* __restrict__ vmask) {
    __shared__ __align__(16) ull tile[RTILE];
    __shared__ int slast;
    int tid = threadIdx.x;
    int bx = blockIdx.x, by = blockIdx.y;
    unsigned C = meta[1]; if (C > CAP) C = CAP;
    int ibase = bx * 256 * RITEMS;
    ull ki[RITEMS]; unsigned cnt[RITEMS];
    #pragma unroll
    for (int r = 0; r < RITEMS; r++) {
        int i = ibase + r * 256 + tid;
        ki[r] = (i < (int)C) ? cand[i] : ~0ull;
        cnt[r] = 0u;
    }
    int j = by * RTILE + tid;
    tile[tid] = (j < (int)C) ? cand[j] : ~0ull;   // pad = +inf
    __syncthreads();
    const ulonglong2* t2 = (const ulonglong2*)tile;
    for (int q = 0; q < RTILE / 2; q++) {
        ulonglong2 v = t2[q];
        #pragma unroll
        for (int r = 0; r < RITEMS; r++)
            cnt[r] += (unsigned)(v.x < ki[r]) + (unsigned)(v.y < ki[r]);
    }
    #pragma unroll
    for (int r = 0; r < RITEMS; r++)
        if (cnt[r]) atomicAdd(&rank[ibase + r * 256 + tid], cnt[r]);
    __syncthreads();
    if (tid == 0) {
        __threadfence();                        // cheap: atomic-only dirty set
        slast = (atomicAdd(&meta[3], 1u) == gridDim.x * gridDim.y - 1);
    }
    __syncthreads();
    if (!slast) return;
    __threadfence();
    for (int i = tid; i < (int)C; i += 256) {
        ull kv = cand[i];
        unsigned uu = ~(unsigned)(kv >> 32);
        if (uu == 0u) continue;                // invalid box
        unsigned r = rank[i];
        if (r >= PRE_NMS) continue;            // outside top-6000
        int idx = (int)(unsigned)kv;
        topbox[r] = decode_box(loc, anc, idx);
        atomicOr(&vmask[r >> 6], 1ull << (r & 63));
    }
}

// ============ K4: suppression matrix + 512-super-chunk diag array =======
// One 64x64 upper-tri tile per wave. Tiles within the same 512-row group
// also write dgsc[sc][r_loc][w_loc] (512x512-bit intra-sc suppression).
// Lower-tri entries unwritten: garbage only ever lands in already-consumed
// scan state words (argument validated R8/R9, absmax 0.0).
__global__ __launch_bounds__(256) void k_supp(const float4* __restrict__ topbox,
                                              ull* __restrict__ supp,
                                              ull* __restrict__ dgsc) {
    __shared__ float4 cbox[256];
    int tid = threadIdx.x, bid = blockIdx.x;
    int wid = tid >> 6, lane = tid & 63;
    float4* cb4 = cbox + wid * 64;
    int vb = bid * 4 + wid;
    if (vb >= KW * KW) return;
    int rb = vb / KW, cb = vb - rb * KW;
    if (cb < rb) return;
    int jt = cb * 64 + lane;
    cb4[lane] = (jt < PRE_NMS) ? topbox[jt] : make_float4(3.f, 3.f, 3.f, 3.f);
    int i = rb * 64 + lane;
    if (i >= PRE_NMS) return;
    float4 bi = topbox[i];
    float ai = (bi.z - bi.x) * (bi.w - bi.y);
    ull bits = 0ull;
    int j0 = cb * 64;
    for (int jj = 0; jj < 64; jj++) {
        int j = j0 + jj;
        if (j <= i || j >= PRE_NMS) continue;
        float4 bj = cb4[jj];
        float aj = (bj.z - bj.x) * (bj.w - bj.y);
        float lx = fmaxf(bi.x, bj.x), ly = fmaxf(bi.y, bj.y);
        float rx = fminf(bi.z, bj.z), ry = fminf(bi.w, bj.w);
        float iw = fmaxf(rx - lx, 0.f), ih = fmaxf(ry - ly, 0.f);
        float inter = iw * ih;
        float iou = inter / (ai + aj - inter + 1e-12f);
        if (iou > IOU_TH) bits |= (1ull << jj);
    }
    supp[(size_t)i * KW + cb] = bits;
    if ((cb >> 3) == (rb >> 3)) {              // intra-super-chunk tile
        size_t o = ((size_t)(rb >> 3) * 512 + (rb & 7) * 64 + lane) * 8 + (cb & 7);
        dgsc[o] = bits;
    }
}

// ============ K5: super-chunked greedy scan (1 block) ===================
// Wave 0 resolves 512 rows from LDS diag (no global loads) while waves 1-3
// stage the next super-chunk's diag; at each boundary all 256 threads merge
// the new keeps' supp rows into a 94-word LDS state (coalesced independent
// loads + LDS atomicOr) -> one wide round trip per super-chunk.
__global__ __launch_bounds__(256) void k_scan(const ull* __restrict__ supp,
                                              const ull* __restrict__ dgsc,
                                              const ull* __restrict__ vmask,
                                              const float4* __restrict__ topbox,
                                              float* __restrict__ out) {
    __shared__ ull dsb[2][4096];               // 64 KB double-buffered diag
    __shared__ ull gstate[KW];                 // suppressed-or-invalid bits
    __shared__ int klist[POST_NMS];
    __shared__ int snk, snew0, sdone;
    int tid = threadIdx.x;
    int wid = tid >> 6, lane = tid & 63;
    if (tid < KW) gstate[tid] = ~vmask[tid];
    if (tid == 0) { snk = 0; sdone = 0; }
    for (int q = tid; q < 4096; q += 256) dsb[0][q] = dgsc[q];
    __syncthreads();
    int cur = 0;
    for (int sc = 0; sc < NSC; sc++) {
        if (wid == 0) {
            if (lane == 0) snew0 = snk;
            int nk = snk;
            ull rA = 0ull;                     // intra-sc state, lane l = word l
            bool done = false;
            for (int cl = 0; cl < 8 && !done; cl++) {
                int c = sc * 8 + cl;
                if (c >= KW) break;
                ull st = gstate[c] | bcast64(rA, cl);
                ull todo = ~st;
                while (todo) {                 // every surviving bit = keep
                    int b = __builtin_ctzll(todo);
                    int row = cl * 64 + b;
                    ull w = (lane < 8) ? dsb[cur][row * 8 + lane] : 0ull;
                    if (lane == 0) klist[nk] = sc * 512 + row;
                    nk++;
                    if (nk == POST_NMS) { done = true; break; }
                    rA |= w;
                    todo &= ~bcast64(w, cl);
                    todo &= ~(1ull << b);
                }
            }
            if (lane == 0) { snk = nk; if (done) sdone = 1; }
        } else if (sc + 1 < NSC) {             // waves 1-3: stage next diag
            const ull* src = dgsc + (size_t)(sc + 1) * 4096;
            for (int q = tid - 64; q < 4096; q += 192) dsb[cur ^ 1][q] = src[q];
        }
        __syncthreads();
        int nk = snk, n0 = snew0, done = sdone;
        if (!done && sc + 1 < NSC) {           // wide merge: all threads
            int nnew = nk - n0;
            for (int p = tid; p < nnew * KW; p += 256) {
                int k = p / KW, w = p - k * KW;
                ull v = supp[(size_t)klist[n0 + k] * KW + w];
                atomicOr(&gstate[w], v);
            }
        }
        __syncthreads();
        if (done) break;
        cur ^= 1;
    }
    int nk = snk;
    for (int q = tid; q < POST_NMS; q += 256)
        ((float4*)out)[q] = (q < nk) ? topbox[klist[q]]
                                     : make_float4(0.f, 0.f, 0.f, 0.f);
}

// =====================  small-ws fallback (R5-validated)  ================
__global__ __launch_bounds__(256) void k_score(const float* __restrict__ cls,
                                               const float* __restrict__ loc,
                                               const float* __restrict__ anc,
                                               unsigned* __restrict__ hist, int n) {
    __shared__ unsigned lh[NBUCK];
    int tid = threadIdx.x, bid = blockIdx.x;
    for (int q = tid; q < NBUCK; q += 256) lh[q] = 0u;
    __syncthreads();
    for (int i = bid * 256 + tid; i < n; i += SBLK * 256) {
        unsigned u = make_key(cls, loc, anc, i);
        atomicAdd(&lh[u >> BSHIFT], 1u);
    }
    __syncthreads();
    for (int qq = 0; qq < NBUCK / 256; qq++) {
        int q = (qq + bid) & (NBUCK / 256 - 1);
        int b = q * 256 + tid;
        unsigned v = lh[b];
        if (v) atomicAdd(&hist[b], v);
    }
}

__global__ __launch_bounds__(1024) void k_findb(const unsigned* __restrict__ hist,
                                                unsigned* __restrict__ meta) {
    __shared__ unsigned ps[1024];
    int t = threadIdx.x;
    int base = t * (NBUCK / 1024);
    unsigned local = 0;
    for (int b = 0; b < NBUCK / 1024; b++) local += hist[base + b];
    ps[t] = local;
    __syncthreads();
    for (int off = 1; off < 1024; off <<= 1) {
        unsigned add = (t + off < 1024) ? ps[t + off] : 0u;
        __syncthreads();
        ps[t] += add;
        __syncthreads();
    }
    unsigned incl = ps[t], excl = incl - local;
    if (incl >= (unsigned)PRE_NMS && excl < (unsigned)PRE_NMS) {
        unsigned cum = excl; int B = base;
        for (int b = NBUCK / 1024 - 1; b >= 0; b--) {
            cum += hist[base + b];
            if (cum >= (unsigned)PRE_NMS) { B = base + b; break; }
        }
        meta[0] = (unsigned)B;
    }
}

__global__ __launch_bounds__(256) void k_rank(const ull* __restrict__ cand,
                                              const unsigned* __restrict__ meta,
                                              unsigned* __restrict__ rank,
                                              float4* __restrict__ topbox) {
    __shared__ __align__(16) ull tile[RTILE];
    int tid = threadIdx.x;
    int bx = blockIdx.x, by = blockIdx.y;
    unsigned C = meta[1]; if (C > CAP) C = CAP;
    if (by == 0) {
        int per = TB_PAD / (CAP / (256 * RITEMS));
        int s0 = bx * per;
        for (int q = tid; q < per; q += 256)
            topbox[s0 + q] = make_float4(-1.f, -1.f, -1.f, -1.f);
    }
    int ibase = bx * 256 * RITEMS;
    ull ki[RITEMS]; unsigned cnt[RITEMS];
    #pragma unroll
    for (int r = 0; r < RITEMS; r++) {
        int i = ibase + r * 256 + tid;
        ki[r] = (i < (int)C) ? cand[i] : ~0ull;
        cnt[r] = 0u;
    }
    int j = by * RTILE + tid;
    tile[tid] = (j < (int)C) ? cand[j] : ~0ull;
    __syncthreads();
    const ulonglong2* t2 = (const ulonglong2*)tile;
    for (int q = 0; q < RTILE / 2; q++) {
        ulonglong2 v = t2[q];
        #pragma unroll
        for (int r = 0; r < RITEMS; r++)
            cnt[r] += (unsigned)(v.x < ki[r]) + (unsigned)(v.y < ki[r]);
    }
    #pragma unroll
    for (int r = 0; r < RITEMS; r++)
        if (cnt[r]) atomicAdd(&rank[ibase + r * 256 + tid], cnt[r]);
}

__global__ __launch_bounds__(256) void k_scatter(const ull* __restrict__ cand,
                                                 const unsigned* __restrict__ meta,
                                                 const unsigned* __restrict__ rank,
                                                 const float* __restrict__ loc,
                                                 const float* __restrict__ anc,
                                                 float4* __restrict__ topbox,
                                                 ull* __restrict__ vmask) {
    int i = blockIdx.x * 256 + threadIdx.x;
    unsigned C = meta[1]; if (C > CAP) C = CAP;
    if (i >= (int)C) return;
    ull kv = cand[i];
    unsigned uu = ~(unsigned)(kv >> 32);
    if (uu == 0u) return;
    unsigned r = rank[i];
    if (r >= PRE_NMS) return;
    int idx = (int)(unsigned)kv;
    topbox[r] = decode_box(loc, anc, idx);
    atomicOr(&vmask[r >> 6], 1ull << (r & 63));
}

__global__ __launch_bounds__(64) void k_nms(const float4* __restrict__ topbox,
                                            float* __restrict__ out) {
    int l = threadIdx.x;
    float4 kb[5];
    int nk = 0;
    for (int q0 = 0; q0 < TB_PAD && nk < POST_NMS; q0 += 64) {
        float4 myb = topbox[q0 + l];
        for (int b = 0; b < 64 && nk < POST_NMS; b++) {
            float4 bb;
            bb.x = __shfl(myb.x, b, 64);
            bb.y = __shfl(myb.y, b, 64);
            bb.z = __shfl(myb.z, b, 64);
            bb.w = __shfl(myb.w, b, 64);
            if (bb.x < 0.f) continue;
            float ab = (bb.z - bb.x) * (bb.w - bb.y);
            bool sup = false;
            #pragma unroll
            for (int r = 0; r < 5; r++) {
                int s = r * 64 + l;
                if (s < nk) {
                    float4 kv = kb[r];
                    float ak = (kv.z - kv.x) * (kv.w - kv.y);
                    float lx = fmaxf(bb.x, kv.x), ly = fmaxf(bb.y, kv.y);
                    float rx = fminf(bb.z, kv.z), ry = fminf(bb.w, kv.w);
                    float iw = fmaxf(rx - lx, 0.f), ih = fmaxf(ry - ly, 0.f);
                    float inter = iw * ih;
                    float iou = inter / (ab + ak - inter + 1e-12f);
                    sup |= (iou > IOU_TH);
                }
            }
            if (!__any(sup)) {
                if (l == (nk & 63)) kb[nk >> 6] = bb;
                if (l < 4) {
                    float v = (l == 0) ? bb.x : (l == 1) ? bb.y : (l == 2) ? bb.z : bb.w;
                    out[4 * nk + l] = v;
                }
                nk++;
            }
        }
    }
    for (int t = nk * 4 + l; t < POST_NMS * 4; t += 64) out[t] = 0.f;
}

extern "C" void kernel_launch(void* const* d_in, const int* in_sizes, int n_in,
                              void* d_out, int out_size, void* d_ws, size_t ws_size,
                              hipStream_t stream) {
    const int N = in_sizes[0] / 2;             // 202500
    const float* cls = (const float*)d_in[0];
    const float* loc = (const float*)d_in[1];
    const float* anc = (const float*)d_in[2];
    float* out = (float*)d_out;

    char* ws = (char*)d_ws;
    size_t off = 0;
    auto take = [&](size_t bytes) {
        size_t o = off;
        off += (bytes + 255) & ~(size_t)255;
        return o;
    };
    // zero region (one memset): hist + meta/vmask + rank
    unsigned* hist = (unsigned*)(ws + take((size_t)NBUCK * 4));      // 64 KB
    char*     mblk = ws + take(1024);
    unsigned* meta  = (unsigned*)mblk;         // [0]=B [1]=C [2..3]=tickets
    ull*      vmask = (ull*)(mblk + 256);      // 94 words
    unsigned* rank = (unsigned*)(ws + take((size_t)CAP * 4));        // 32 KB
    size_t zlen = off;
    ull*    cand   = (ull*)(ws + take((size_t)CAP * 8));             // 64 KB
    float4* topbox = (float4*)(ws + take((size_t)TB_PAD * 16));      // 94 KB
    ull*    dgsc   = (ull*)(ws + take((size_t)NSC * 4096 * 8));      // 384 KB
    ull*    supp   = (ull*)(ws + take((size_t)PRE_NMS * KW * 8));    // 4.42 MB
    size_t full_need = off;
    const bool fast = (ws_size >= full_need);   // constant across calls

    hipMemsetAsync(ws, 0, zlen, stream);

    if (fast) {
        k_score_fb<<<SBLK, 256, 0, stream>>>(cls, loc, anc, hist, meta, N);
        k_compactR<<<(N + 255) / 256, 256, 0, stream>>>(cls, loc, anc, meta, cand, N);
        k_rank_sc<<<dim3(CAP / (256 * RITEMS), CAP / RTILE), 256, 0, stream>>>(
            cand, meta, rank, loc, anc, topbox, vmask);
        k_supp<<<(KW * KW + 3) / 4, 256, 0, stream>>>(topbox, supp, dgsc);
        k_scan<<<1, 256, 0, stream>>>(supp, dgsc, vmask, topbox, out);
    } else {
        k_score<<<SBLK, 256, 0, stream>>>(cls, loc, anc, hist, N);
        k_findb<<<1, 1024, 0, stream>>>(hist, meta);
        k_compactR<<<(N + 255) / 256, 256, 0, stream>>>(cls, loc, anc, meta, cand, N);
        k_rank<<<dim3(CAP / (256 * RITEMS), CAP / RTILE), 256, 0, stream>>>(cand, meta, rank, topbox);
        k_scatter<<<CAP / 256, 256, 0, stream>>>(cand, meta, rank, loc, anc, topbox, vmask);
        k_nms<<<1, 64, 0, stream>>>(topbox, out);
    }
}